// Round 1
// baseline (971.045 us; speedup 1.0000x reference)
//
#include <hip/hip_runtime.h>
#include <cstdint>
#include <cstddef>
#include <cmath>

#define D 128

// ======================= CSR build =======================
__global__ void k_degree(const int* __restrict__ dst, int E, int* __restrict__ deg) {
  int e = blockIdx.x * blockDim.x + threadIdx.x;
  if (e < E) atomicAdd(&deg[dst[e]], 1);
}

#define SCAN_T 256
#define SCAN_E 4
#define SCAN_CHUNK (SCAN_T * SCAN_E)

__global__ void k_scan_partial(const int* __restrict__ deg, int n, int* __restrict__ part) {
  __shared__ int s[SCAN_T];
  int base = blockIdx.x * SCAN_CHUNK;
  int sum = 0;
  for (int i = 0; i < SCAN_E; ++i) {
    int idx = base + (int)threadIdx.x * SCAN_E + i;
    if (idx < n) sum += deg[idx];
  }
  s[threadIdx.x] = sum; __syncthreads();
  for (int ofs = SCAN_T / 2; ofs > 0; ofs >>= 1) {
    if ((int)threadIdx.x < ofs) s[threadIdx.x] += s[threadIdx.x + ofs];
    __syncthreads();
  }
  if (threadIdx.x == 0) part[blockIdx.x] = s[0];
}

__global__ void k_scan_part_ex(int* __restrict__ part, int nb) {
  __shared__ int s[1024];
  int v = ((int)threadIdx.x < nb) ? part[threadIdx.x] : 0;
  s[threadIdx.x] = v; __syncthreads();
  for (int ofs = 1; ofs < 1024; ofs <<= 1) {
    int t = ((int)threadIdx.x >= ofs) ? s[threadIdx.x - ofs] : 0;
    __syncthreads();
    s[threadIdx.x] += t;
    __syncthreads();
  }
  if ((int)threadIdx.x < nb) part[threadIdx.x] = s[threadIdx.x] - v;  // exclusive
}

__global__ void k_scan_final(const int* __restrict__ deg, int n, const int* __restrict__ part,
                             int* __restrict__ rowptr, int E) {
  __shared__ int s[SCAN_T];
  int base = blockIdx.x * SCAN_CHUNK;
  int v[SCAN_E]; int local = 0;
  for (int i = 0; i < SCAN_E; ++i) {
    int idx = base + (int)threadIdx.x * SCAN_E + i;
    v[i] = (idx < n) ? deg[idx] : 0;
    local += v[i];
  }
  s[threadIdx.x] = local; __syncthreads();
  for (int ofs = 1; ofs < SCAN_T; ofs <<= 1) {
    int t = ((int)threadIdx.x >= ofs) ? s[threadIdx.x - ofs] : 0;
    __syncthreads();
    s[threadIdx.x] += t;
    __syncthreads();
  }
  int run = part[blockIdx.x] + s[threadIdx.x] - local;  // exclusive prefix
  for (int i = 0; i < SCAN_E; ++i) {
    int idx = base + (int)threadIdx.x * SCAN_E + i;
    if (idx < n) rowptr[idx] = run;
    run += v[i];
  }
  if (blockIdx.x == 0 && threadIdx.x == 0) rowptr[n] = E;
}

__global__ void k_fill(const int* __restrict__ src, const int* __restrict__ dst, int E,
                       int* __restrict__ cursor, int* __restrict__ csrc) {
  int e = blockIdx.x * blockDim.x + threadIdx.x;
  if (e < E) {
    int p = atomicAdd(&cursor[dst[e]], 1);
    csrc[p] = src[e];
  }
}

// ======================= mean aggregation (wave per node) =======================
__global__ __launch_bounds__(256) void k_aggregate(const float* __restrict__ h,
    const int* __restrict__ rowptr, const int* __restrict__ csrc,
    float* __restrict__ hn, int N) {
  int wid = (int)((blockIdx.x * (size_t)blockDim.x + threadIdx.x) >> 6);
  int lane = threadIdx.x & 63;
  if (wid >= N) return;
  int beg = rowptr[wid], end = rowptr[wid + 1];
  float2 acc = make_float2(0.f, 0.f);
  const float2* h2 = (const float2*)h;
  for (int i = beg; i < end; ++i) {
    int s = csrc[i];  // wave-uniform
    float2 v = h2[(size_t)s * 64 + lane];
    acc.x += v.x; acc.y += v.y;
  }
  float inv = (end > beg) ? (1.0f / (float)(end - beg)) : 0.0f;
  ((float2*)hn)[(size_t)wid * 64 + lane] = make_float2(acc.x * inv, acc.y * inv);
}

// ======================= fused SAGE layer GEMM =======================
// out[r][j] = relu?( sum_k A[r][k]*Ws[k][j] + An[r][k]*Wn[k][j] + b[j] )
#define GR 32   // rows per block
#define GKC 64  // k chunk
__global__ __launch_bounds__(256) void k_sage_gemm(
    const float* __restrict__ A, const float* __restrict__ An,
    const float* __restrict__ Ws, const float* __restrict__ Wn,
    const float* __restrict__ bias, float* __restrict__ out, int do_relu) {
  __shared__ float sA[GR][GKC];   // 8 KB
  __shared__ float sW[GKC][D];    // 32 KB
  int tid = threadIdx.x;
  int tx = tid & 31, ry = tid >> 5;
  int row0 = blockIdx.x * GR;
  int r0 = ry * 4, j0 = tx * 4;
  float acc[4][4] = {{0.f}};

  for (int kc = 0; kc < 4; ++kc) {
    const float* Asrc = (kc < 2) ? A : An;
    const float* Wsrc = (kc < 2) ? Ws : Wn;
    int kbase = (kc & 1) * GKC;
    __syncthreads();  // protect LDS reuse across chunks
    // A tile: 32 rows x 64 k (512 float4, 2 per thread)
    #pragma unroll
    for (int i = 0; i < 2; ++i) {
      int f = i * 256 + tid;
      int r = f >> 4, k4 = f & 15;
      float4 v = *(const float4*)(Asrc + (size_t)(row0 + r) * D + kbase + k4 * 4);
      *(float4*)&sA[r][k4 * 4] = v;
    }
    // W tile: 64 k x 128 cols (2048 float4, 8 per thread)
    #pragma unroll
    for (int i = 0; i < 8; ++i) {
      int f = i * 256 + tid;
      int kr = f >> 5, c4 = f & 31;
      float4 v = *(const float4*)(Wsrc + (size_t)(kbase + kr) * D + c4 * 4);
      *(float4*)&sW[kr][c4 * 4] = v;
    }
    __syncthreads();
    #pragma unroll
    for (int k = 0; k < GKC; k += 4) {
      float4 a[4], w[4];
      #pragma unroll
      for (int rr = 0; rr < 4; ++rr) a[rr] = *(const float4*)&sA[r0 + rr][k];
      #pragma unroll
      for (int kk = 0; kk < 4; ++kk) w[kk] = *(const float4*)&sW[k + kk][j0];
      #pragma unroll
      for (int rr = 0; rr < 4; ++rr) {
        float ar[4] = {a[rr].x, a[rr].y, a[rr].z, a[rr].w};
        #pragma unroll
        for (int kk = 0; kk < 4; ++kk) {
          acc[rr][0] += ar[kk] * w[kk].x;
          acc[rr][1] += ar[kk] * w[kk].y;
          acc[rr][2] += ar[kk] * w[kk].z;
          acc[rr][3] += ar[kk] * w[kk].w;
        }
      }
    }
  }
  float4 bj = *(const float4*)(bias + j0);
  #pragma unroll
  for (int rr = 0; rr < 4; ++rr) {
    float4 o;
    o.x = acc[rr][0] + bj.x; o.y = acc[rr][1] + bj.y;
    o.z = acc[rr][2] + bj.z; o.w = acc[rr][3] + bj.w;
    if (do_relu) {
      o.x = fmaxf(o.x, 0.f); o.y = fmaxf(o.y, 0.f);
      o.z = fmaxf(o.z, 0.f); o.w = fmaxf(o.w, 0.f);
    }
    *(float4*)(out + (size_t)(row0 + r0 + rr) * D + j0) = o;
  }
}

// ======================= fused predictor MLP =======================
#define PKC 32
__global__ __launch_bounds__(256) void k_predict(
    const float* __restrict__ h, const int* __restrict__ sidx, const int* __restrict__ didx,
    const float* __restrict__ Wp0, const float* __restrict__ bp0,
    const float* __restrict__ Wp1, const float* __restrict__ bp1,
    const float* __restrict__ Wp2, const float* __restrict__ bp2,
    float* __restrict__ outp) {
  __shared__ float sZ[GR][D];    // 16 KB
  __shared__ float sZ2[GR][D];   // 16 KB
  __shared__ float sW[PKC][D];   // 16 KB
  int tid = threadIdx.x;
  int row0 = blockIdx.x * GR;
  // gather + hadamard: z = h[s] * h[d]
  {
    int r = tid >> 3, q = tid & 7;
    int prow = row0 + r;
    int si = sidx[prow], di = didx[prow];
    const float4* hs = (const float4*)(h + (size_t)si * D);
    const float4* hd = (const float4*)(h + (size_t)di * D);
    #pragma unroll
    for (int i = 0; i < 4; ++i) {
      int c4 = i * 8 + q;
      float4 a = hs[c4], b = hd[c4];
      float4 z; z.x = a.x * b.x; z.y = a.y * b.y; z.z = a.z * b.z; z.w = a.w * b.w;
      *(float4*)&sZ[r][c4 * 4] = z;
    }
  }
  int tx = tid & 31, ry = tid >> 5;
  int r0 = ry * 4, j0 = tx * 4;
  float acc[4][4] = {{0.f}};
  // GEMM1: relu(sZ @ Wp0 + bp0) -> sZ2
  for (int kc = 0; kc < 4; ++kc) {
    __syncthreads();
    #pragma unroll
    for (int i = 0; i < 4; ++i) {
      int f = i * 256 + tid;
      int kr = f >> 5, c4 = f & 31;
      *(float4*)&sW[kr][c4 * 4] = *(const float4*)(Wp0 + (size_t)(kc * PKC + kr) * D + c4 * 4);
    }
    __syncthreads();
    #pragma unroll
    for (int k = 0; k < PKC; k += 4) {
      int kg = kc * PKC + k;
      float4 a[4], w[4];
      #pragma unroll
      for (int rr = 0; rr < 4; ++rr) a[rr] = *(const float4*)&sZ[r0 + rr][kg];
      #pragma unroll
      for (int kk = 0; kk < 4; ++kk) w[kk] = *(const float4*)&sW[k + kk][j0];
      #pragma unroll
      for (int rr = 0; rr < 4; ++rr) {
        float ar[4] = {a[rr].x, a[rr].y, a[rr].z, a[rr].w};
        #pragma unroll
        for (int kk = 0; kk < 4; ++kk) {
          acc[rr][0] += ar[kk] * w[kk].x;
          acc[rr][1] += ar[kk] * w[kk].y;
          acc[rr][2] += ar[kk] * w[kk].z;
          acc[rr][3] += ar[kk] * w[kk].w;
        }
      }
    }
  }
  {
    float4 bv = *(const float4*)(bp0 + j0);
    float bb[4] = {bv.x, bv.y, bv.z, bv.w};
    #pragma unroll
    for (int rr = 0; rr < 4; ++rr) {
      float4 o;
      o.x = fmaxf(acc[rr][0] + bb[0], 0.f);
      o.y = fmaxf(acc[rr][1] + bb[1], 0.f);
      o.z = fmaxf(acc[rr][2] + bb[2], 0.f);
      o.w = fmaxf(acc[rr][3] + bb[3], 0.f);
      *(float4*)&sZ2[r0 + rr][j0] = o;
      acc[rr][0] = acc[rr][1] = acc[rr][2] = acc[rr][3] = 0.f;
    }
  }
  // GEMM2: relu(sZ2 @ Wp1 + bp1) -> regs
  for (int kc = 0; kc < 4; ++kc) {
    __syncthreads();  // also makes sZ2 visible on kc==0
    #pragma unroll
    for (int i = 0; i < 4; ++i) {
      int f = i * 256 + tid;
      int kr = f >> 5, c4 = f & 31;
      *(float4*)&sW[kr][c4 * 4] = *(const float4*)(Wp1 + (size_t)(kc * PKC + kr) * D + c4 * 4);
    }
    __syncthreads();
    #pragma unroll
    for (int k = 0; k < PKC; k += 4) {
      int kg = kc * PKC + k;
      float4 a[4], w[4];
      #pragma unroll
      for (int rr = 0; rr < 4; ++rr) a[rr] = *(const float4*)&sZ2[r0 + rr][kg];
      #pragma unroll
      for (int kk = 0; kk < 4; ++kk) w[kk] = *(const float4*)&sW[k + kk][j0];
      #pragma unroll
      for (int rr = 0; rr < 4; ++rr) {
        float ar[4] = {a[rr].x, a[rr].y, a[rr].z, a[rr].w};
        #pragma unroll
        for (int kk = 0; kk < 4; ++kk) {
          acc[rr][0] += ar[kk] * w[kk].x;
          acc[rr][1] += ar[kk] * w[kk].y;
          acc[rr][2] += ar[kk] * w[kk].z;
          acc[rr][3] += ar[kk] * w[kk].w;
        }
      }
    }
  }
  // final: logits = z2 @ Wp2 + bp2 ; out = sigmoid(l1 - l0)
  {
    float4 bv = *(const float4*)(bp1 + j0);
    float bb[4] = {bv.x, bv.y, bv.z, bv.w};
    float z2[4][4];
    #pragma unroll
    for (int rr = 0; rr < 4; ++rr)
      #pragma unroll
      for (int cc = 0; cc < 4; ++cc)
        z2[rr][cc] = fmaxf(acc[rr][cc] + bb[cc], 0.f);
    float w2a[4], w2b[4];
    #pragma unroll
    for (int cc = 0; cc < 4; ++cc) {
      w2a[cc] = Wp2[(size_t)(j0 + cc) * 2 + 0];
      w2b[cc] = Wp2[(size_t)(j0 + cc) * 2 + 1];
    }
    float p0[4] = {0.f, 0.f, 0.f, 0.f}, p1[4] = {0.f, 0.f, 0.f, 0.f};
    #pragma unroll
    for (int rr = 0; rr < 4; ++rr)
      #pragma unroll
      for (int cc = 0; cc < 4; ++cc) {
        p0[rr] += z2[rr][cc] * w2a[cc];
        p1[rr] += z2[rr][cc] * w2b[cc];
      }
    #pragma unroll
    for (int m = 1; m <= 16; m <<= 1) {
      #pragma unroll
      for (int rr = 0; rr < 4; ++rr) {
        p0[rr] += __shfl_xor(p0[rr], m);
        p1[rr] += __shfl_xor(p1[rr], m);
      }
    }
    if (tx == 0) {
      float c0 = bp2[0], c1 = bp2[1];
      #pragma unroll
      for (int rr = 0; rr < 4; ++rr) {
        float l0 = p0[rr] + c0, l1 = p1[rr] + c1;
        outp[row0 + r0 + rr] = 1.0f / (1.0f + expf(l0 - l1));
      }
    }
  }
}

// ======================= launch =======================
extern "C" void kernel_launch(void* const* d_in, const int* in_sizes, int n_in,
                              void* d_out, int out_size, void* d_ws, size_t ws_size,
                              hipStream_t stream) {
  const float* x       = (const float*)d_in[0];
  const int*   src     = (const int*)d_in[1];
  const int*   dst     = (const int*)d_in[2];
  const int*   pos_src = (const int*)d_in[3];
  const int*   pos_dst = (const int*)d_in[4];
  const int*   neg_src = (const int*)d_in[5];
  const int*   neg_dst = (const int*)d_in[6];
  const float* Ws0 = (const float*)d_in[7],  *Wn0 = (const float*)d_in[8],  *b0 = (const float*)d_in[9];
  const float* Ws1 = (const float*)d_in[10], *Wn1 = (const float*)d_in[11], *b1 = (const float*)d_in[12];
  const float* Ws2 = (const float*)d_in[13], *Wn2 = (const float*)d_in[14], *b2 = (const float*)d_in[15];
  const float* Wp0 = (const float*)d_in[16], *bp0 = (const float*)d_in[17];
  const float* Wp1 = (const float*)d_in[18], *bp1 = (const float*)d_in[19];
  const float* Wp2 = (const float*)d_in[20], *bp2 = (const float*)d_in[21];
  const int N = in_sizes[0] / D;
  const int E = in_sizes[1];
  const int P = in_sizes[3];
  float* outp = (float*)d_out;

  char* ws = (char*)d_ws;
  size_t off = 0;
  auto alloc = [&](size_t bytes) -> void* {
    void* p = ws + off;
    off += (bytes + 255) & ~(size_t)255;
    return p;
  };
  float* hA     = (float*)alloc((size_t)N * D * 4);
  float* hB     = (float*)alloc((size_t)N * D * 4);
  float* hn     = (float*)alloc((size_t)N * D * 4);
  int*   deg    = (int*)alloc((size_t)N * 4);
  int*   rowptr = (int*)alloc((size_t)(N + 1) * 4);
  int*   cursor = (int*)alloc((size_t)N * 4);
  int*   part   = (int*)alloc(4096);
  int*   csrc   = (int*)alloc((size_t)E * 4);
  (void)ws_size; (void)n_in; (void)out_size;

  // --- CSR build (once; shared by all 3 layers) ---
  hipMemsetAsync(deg, 0, (size_t)N * 4, stream);
  int eb = (E + 255) / 256;
  k_degree<<<eb, 256, 0, stream>>>(dst, E, deg);
  int nb = (N + SCAN_CHUNK - 1) / SCAN_CHUNK;
  k_scan_partial<<<nb, SCAN_T, 0, stream>>>(deg, N, part);
  k_scan_part_ex<<<1, 1024, 0, stream>>>(part, nb);
  k_scan_final<<<nb, SCAN_T, 0, stream>>>(deg, N, part, rowptr, E);
  hipMemcpyAsync(cursor, rowptr, (size_t)N * 4, hipMemcpyDeviceToDevice, stream);
  k_fill<<<eb, 256, 0, stream>>>(src, dst, E, cursor, csrc);

  int aggb = (int)(((size_t)N * 64 + 255) / 256);
  int gemb = (N + GR - 1) / GR;
  // layer 0
  k_aggregate<<<aggb, 256, 0, stream>>>(x, rowptr, csrc, hn, N);
  k_sage_gemm<<<gemb, 256, 0, stream>>>(x, hn, Ws0, Wn0, b0, hA, 1);
  // layer 1
  k_aggregate<<<aggb, 256, 0, stream>>>(hA, rowptr, csrc, hn, N);
  k_sage_gemm<<<gemb, 256, 0, stream>>>(hA, hn, Ws1, Wn1, b1, hB, 1);
  // layer 2 (no relu)
  k_aggregate<<<aggb, 256, 0, stream>>>(hB, rowptr, csrc, hn, N);
  k_sage_gemm<<<gemb, 256, 0, stream>>>(hB, hn, Ws2, Wn2, b2, hA, 0);
  // predictor (pos then neg)
  int pb = (P + GR - 1) / GR;
  k_predict<<<pb, 256, 0, stream>>>(hA, pos_src, pos_dst, Wp0, bp0, Wp1, bp1, Wp2, bp2, outp);
  k_predict<<<pb, 256, 0, stream>>>(hA, neg_src, neg_dst, Wp0, bp0, Wp1, bp1, Wp2, bp2, outp + P);
}

// Round 2
// 633.682 us; speedup vs baseline: 1.5324x; 1.5324x over previous
//
#include <hip/hip_runtime.h>
#include <cstdint>
#include <cstddef>
#include <cmath>

#define D 128

typedef short bf16x8 __attribute__((ext_vector_type(8)));
typedef float f32x4 __attribute__((ext_vector_type(4)));

__device__ __forceinline__ ushort f2b(float f) {
  uint x = __float_as_uint(f);
  uint r = ((x >> 16) & 1u) + 0x7fffu;   // round-to-nearest-even
  return (ushort)((x + r) >> 16);
}
__device__ __forceinline__ float b2f(ushort u) {
  return __uint_as_float(((uint)u) << 16);
}

// ======================= CSR build =======================
__global__ void k_degree(const int* __restrict__ dst, int E, int* __restrict__ deg) {
  int e = blockIdx.x * blockDim.x + threadIdx.x;
  if (e < E) atomicAdd(&deg[dst[e]], 1);
}

#define SCAN_T 256
#define SCAN_E 4
#define SCAN_CHUNK (SCAN_T * SCAN_E)

__global__ void k_scan_partial(const int* __restrict__ deg, int n, int* __restrict__ part) {
  __shared__ int s[SCAN_T];
  int base = blockIdx.x * SCAN_CHUNK;
  int sum = 0;
  for (int i = 0; i < SCAN_E; ++i) {
    int idx = base + (int)threadIdx.x * SCAN_E + i;
    if (idx < n) sum += deg[idx];
  }
  s[threadIdx.x] = sum; __syncthreads();
  for (int ofs = SCAN_T / 2; ofs > 0; ofs >>= 1) {
    if ((int)threadIdx.x < ofs) s[threadIdx.x] += s[threadIdx.x + ofs];
    __syncthreads();
  }
  if (threadIdx.x == 0) part[blockIdx.x] = s[0];
}

__global__ void k_scan_part_ex(int* __restrict__ part, int nb) {
  __shared__ int s[1024];
  int v = ((int)threadIdx.x < nb) ? part[threadIdx.x] : 0;
  s[threadIdx.x] = v; __syncthreads();
  for (int ofs = 1; ofs < 1024; ofs <<= 1) {
    int t = ((int)threadIdx.x >= ofs) ? s[threadIdx.x - ofs] : 0;
    __syncthreads();
    s[threadIdx.x] += t;
    __syncthreads();
  }
  if ((int)threadIdx.x < nb) part[threadIdx.x] = s[threadIdx.x] - v;  // exclusive
}

__global__ void k_scan_final(const int* __restrict__ deg, int n, const int* __restrict__ part,
                             int* __restrict__ rowptr, int E) {
  __shared__ int s[SCAN_T];
  int base = blockIdx.x * SCAN_CHUNK;
  int v[SCAN_E]; int local = 0;
  for (int i = 0; i < SCAN_E; ++i) {
    int idx = base + (int)threadIdx.x * SCAN_E + i;
    v[i] = (idx < n) ? deg[idx] : 0;
    local += v[i];
  }
  s[threadIdx.x] = local; __syncthreads();
  for (int ofs = 1; ofs < SCAN_T; ofs <<= 1) {
    int t = ((int)threadIdx.x >= ofs) ? s[threadIdx.x - ofs] : 0;
    __syncthreads();
    s[threadIdx.x] += t;
    __syncthreads();
  }
  int run = part[blockIdx.x] + s[threadIdx.x] - local;  // exclusive prefix
  for (int i = 0; i < SCAN_E; ++i) {
    int idx = base + (int)threadIdx.x * SCAN_E + i;
    if (idx < n) rowptr[idx] = run;
    run += v[i];
  }
  if (blockIdx.x == 0 && threadIdx.x == 0) rowptr[n] = E;
}

__global__ void k_fill(const int* __restrict__ src, const int* __restrict__ dst, int E,
                       int* __restrict__ cursor, int* __restrict__ csrc) {
  int e = blockIdx.x * blockDim.x + threadIdx.x;
  if (e < E) {
    int p = atomicAdd(&cursor[dst[e]], 1);
    csrc[p] = src[e];
  }
}

// ======================= fp32 -> bf16 convert =======================
__global__ void k_conv_bf16(const float* __restrict__ in, ushort* __restrict__ out, int n8) {
  int i = blockIdx.x * 256 + threadIdx.x;
  if (i >= n8) return;
  float4 a = ((const float4*)in)[i * 2];
  float4 b = ((const float4*)in)[i * 2 + 1];
  ushort4 o0 = {f2b(a.x), f2b(a.y), f2b(a.z), f2b(a.w)};
  ushort4 o1 = {f2b(b.x), f2b(b.y), f2b(b.z), f2b(b.w)};
  ((ushort4*)out)[i * 2] = o0;
  ((ushort4*)out)[i * 2 + 1] = o1;
}

// ======================= pack weights to B-fragment order =======================
// packed[((ks*8 + t)*64 + lane)*8 + j] = W[ks*32 + (lane>>4)*8 + j][t*16 + (lane&15)]
// virtual W: k<128 -> W0[k][n], k>=128 -> W1[k-128][n]
__global__ void k_packW(const float* __restrict__ W0, const float* __restrict__ W1,
                        ushort* __restrict__ out, int ksteps) {
  int o = blockIdx.x * 256 + threadIdx.x;
  int total = ksteps * 4096;
  if (o >= total) return;
  int j = o & 7, lane = (o >> 3) & 63, t = (o >> 9) & 7, ks = o >> 12;
  int k = ks * 32 + ((lane >> 4) * 8) + j;
  int n = t * 16 + (lane & 15);
  const float* W = (k < 128) ? W0 : W1;
  int kk = (k < 128) ? k : k - 128;
  out[o] = f2b(W[(size_t)kk * D + n]);
}

// ======================= mean aggregation (wave per node, bf16) ================
__global__ __launch_bounds__(256) void k_aggregate_b(const ushort* __restrict__ h,
    const int* __restrict__ rowptr, const int* __restrict__ csrc,
    ushort* __restrict__ hn, int N) {
  int wid = (int)((blockIdx.x * (size_t)blockDim.x + threadIdx.x) >> 6);
  int lane = threadIdx.x & 63;
  if (wid >= N) return;
  int beg = rowptr[wid], end = rowptr[wid + 1];
  float ax = 0.f, ay = 0.f;
  const uint* h2 = (const uint*)h;
  for (int i = beg; i < end; ++i) {
    int s = csrc[i];  // wave-uniform
    uint v = h2[(size_t)s * 64 + lane];
    ax += __uint_as_float(v << 16);
    ay += __uint_as_float(v & 0xffff0000u);
  }
  float inv = (end > beg) ? (1.0f / (float)(end - beg)) : 0.0f;
  ax *= inv; ay *= inv;
  ((uint*)hn)[(size_t)wid * 64 + lane] = ((uint)f2b(ay) << 16) | (uint)f2b(ax);
}

// ======================= SAGE layer GEMM (MFMA, no LDS) =======================
// out[r][c] = act( sum_k A[r][k] Ws[k][c] + An[r][k] Wn[k][c] + b[c] )
// virtual K=256: ks 0..3 from A/Ws, ks 4..7 from An/Wn (baked into packed Bp).
__global__ __launch_bounds__(256) void k_gemm_mfma(
    const ushort* __restrict__ A, const ushort* __restrict__ An,
    const ushort* __restrict__ Bp, const float* __restrict__ bias,
    ushort* __restrict__ out, int N, int do_relu) {
  int tid = threadIdx.x;
  int wave = tid >> 6, lane = tid & 63;
  int m = lane & 15, kg = lane >> 4;
  int row0 = blockIdx.x * 64 + wave * 16;
  int ar = row0 + m; if (ar >= N) ar = N - 1;   // clamp reads; stores guarded
  const ushort* a_self = A  + (size_t)ar * D + kg * 8;
  const ushort* a_nei  = An + (size_t)ar * D + kg * 8;
  f32x4 acc[8];
  #pragma unroll
  for (int t = 0; t < 8; ++t) acc[t] = f32x4{0.f, 0.f, 0.f, 0.f};
  #pragma unroll
  for (int ks = 0; ks < 8; ++ks) {
    const ushort* ap = (ks < 4) ? a_self : a_nei;
    bf16x8 af = *(const bf16x8*)(ap + (ks & 3) * 32);
    const ushort* bb = Bp + (size_t)ks * 4096 + lane * 8;
    #pragma unroll
    for (int t = 0; t < 8; ++t)
      acc[t] = __builtin_amdgcn_mfma_f32_16x16x32_bf16(af, *(const bf16x8*)(bb + t * 512), acc[t], 0, 0, 0);
  }
  #pragma unroll
  for (int t = 0; t < 8; ++t) {
    int c = t * 16 + m;
    float bv = bias[c];
    #pragma unroll
    for (int i = 0; i < 4; ++i) {
      int r = row0 + kg * 4 + i;
      float v = acc[t][i] + bv;
      if (do_relu) v = fmaxf(v, 0.f);
      if (r < N) out[(size_t)r * D + c] = f2b(v);
    }
  }
}

// ======================= fused predictor MLP (MFMA) =======================
__global__ __launch_bounds__(256) void k_predict_mfma(
    const ushort* __restrict__ h, const int* __restrict__ sidx, const int* __restrict__ didx,
    const ushort* __restrict__ Bp0, const float* __restrict__ bp0,
    const ushort* __restrict__ Bp1, const float* __restrict__ bp1,
    const float* __restrict__ Wp2, const float* __restrict__ bp2,
    float* __restrict__ outp, int P) {
  __shared__ __align__(16) ushort z1p[4][2048];  // per-wave A-frag-packed z1 (4 KB/wave)
  int tid = threadIdx.x;
  int wave = tid >> 6, lane = tid & 63;
  int m = lane & 15, kg = lane >> 4;
  int pair0 = blockIdx.x * 64 + wave * 16;
  int prow = pair0 + m; int pr = (prow < P) ? prow : P - 1;
  int si = sidx[pr], di = didx[pr];
  const ushort* hs = h + (size_t)si * D + kg * 8;
  const ushort* hd = h + (size_t)di * D + kg * 8;
  f32x4 acc[8];
  #pragma unroll
  for (int t = 0; t < 8; ++t) acc[t] = f32x4{0.f, 0.f, 0.f, 0.f};
  // ---- GEMM1: z = hs*hd ; acc = z @ Wp0 ----
  #pragma unroll
  for (int ks = 0; ks < 4; ++ks) {
    bf16x8 as8 = *(const bf16x8*)(hs + ks * 32);
    bf16x8 ad8 = *(const bf16x8*)(hd + ks * 32);
    bf16x8 af;
    #pragma unroll
    for (int j = 0; j < 8; ++j) {
      float p = b2f((ushort)as8[j]) * b2f((ushort)ad8[j]);
      af[j] = (short)f2b(p);
    }
    const ushort* bb = Bp0 + (size_t)ks * 4096 + lane * 8;
    #pragma unroll
    for (int t = 0; t < 8; ++t)
      acc[t] = __builtin_amdgcn_mfma_f32_16x16x32_bf16(af, *(const bf16x8*)(bb + t * 512), acc[t], 0, 0, 0);
  }
  // ---- epilogue1: relu(acc + bp0) -> LDS in GEMM2 A-fragment packed order ----
  ushort* zp = &z1p[wave][0];
  #pragma unroll
  for (int t = 0; t < 8; ++t) {
    int c = t * 16 + m;
    float bv = bp0[c];
    int ks2 = c >> 5, kg2 = (c >> 3) & 3, j2 = c & 7;
    #pragma unroll
    for (int i = 0; i < 4; ++i) {
      float v = fmaxf(acc[t][i] + bv, 0.f);
      int l2 = kg2 * 16 + kg * 4 + i;     // consumer lane
      zp[(ks2 * 64 + l2) * 8 + j2] = f2b(v);
    }
  }
  __syncthreads();
  // ---- GEMM2: acc = z1 @ Wp1 ----
  #pragma unroll
  for (int t = 0; t < 8; ++t) acc[t] = f32x4{0.f, 0.f, 0.f, 0.f};
  #pragma unroll
  for (int ks = 0; ks < 4; ++ks) {
    bf16x8 af = *(const bf16x8*)(zp + (ks * 64 + lane) * 8);
    const ushort* bb = Bp1 + (size_t)ks * 4096 + lane * 8;
    #pragma unroll
    for (int t = 0; t < 8; ++t)
      acc[t] = __builtin_amdgcn_mfma_f32_16x16x32_bf16(af, *(const bf16x8*)(bb + t * 512), acc[t], 0, 0, 0);
  }
  // ---- final: z2 = relu(acc + bp1); logits = z2 @ Wp2 + bp2; sigmoid ----
  float p0[4] = {0.f, 0.f, 0.f, 0.f}, p1[4] = {0.f, 0.f, 0.f, 0.f};
  #pragma unroll
  for (int t = 0; t < 8; ++t) {
    int c = t * 16 + m;
    float bv = bp1[c];
    float wa = Wp2[(size_t)c * 2], wb = Wp2[(size_t)c * 2 + 1];
    #pragma unroll
    for (int i = 0; i < 4; ++i) {
      float z = fmaxf(acc[t][i] + bv, 0.f);
      p0[i] += z * wa;
      p1[i] += z * wb;
    }
  }
  #pragma unroll
  for (int msk = 1; msk <= 8; msk <<= 1) {
    #pragma unroll
    for (int i = 0; i < 4; ++i) {
      p0[i] += __shfl_xor(p0[i], msk);
      p1[i] += __shfl_xor(p1[i], msk);
    }
  }
  if (m == 0) {
    float c0 = bp2[0], c1 = bp2[1];
    #pragma unroll
    for (int i = 0; i < 4; ++i) {
      int r = pair0 + kg * 4 + i;
      if (r < P) {
        float l0 = p0[i] + c0, l1 = p1[i] + c1;
        outp[r] = 1.0f / (1.0f + expf(l0 - l1));
      }
    }
  }
}

// ======================= launch =======================
extern "C" void kernel_launch(void* const* d_in, const int* in_sizes, int n_in,
                              void* d_out, int out_size, void* d_ws, size_t ws_size,
                              hipStream_t stream) {
  const float* x       = (const float*)d_in[0];
  const int*   src     = (const int*)d_in[1];
  const int*   dst     = (const int*)d_in[2];
  const int*   pos_src = (const int*)d_in[3];
  const int*   pos_dst = (const int*)d_in[4];
  const int*   neg_src = (const int*)d_in[5];
  const int*   neg_dst = (const int*)d_in[6];
  const float* Ws0 = (const float*)d_in[7],  *Wn0 = (const float*)d_in[8],  *b0 = (const float*)d_in[9];
  const float* Ws1 = (const float*)d_in[10], *Wn1 = (const float*)d_in[11], *b1 = (const float*)d_in[12];
  const float* Ws2 = (const float*)d_in[13], *Wn2 = (const float*)d_in[14], *b2 = (const float*)d_in[15];
  const float* Wp0 = (const float*)d_in[16], *bp0 = (const float*)d_in[17];
  const float* Wp1 = (const float*)d_in[18], *bp1 = (const float*)d_in[19];
  const float* Wp2 = (const float*)d_in[20], *bp2 = (const float*)d_in[21];
  const int N = in_sizes[0] / D;
  const int E = in_sizes[1];
  const int P = in_sizes[3];
  float* outp = (float*)d_out;

  char* ws = (char*)d_ws;
  size_t off = 0;
  auto alloc = [&](size_t bytes) -> void* {
    void* p = ws + off;
    off += (bytes + 255) & ~(size_t)255;
    return p;
  };
  ushort* xb    = (ushort*)alloc((size_t)N * D * 2);
  ushort* h1    = (ushort*)alloc((size_t)N * D * 2);
  ushort* h2    = (ushort*)alloc((size_t)N * D * 2);
  ushort* hn    = (ushort*)alloc((size_t)N * D * 2);
  ushort* BpL0  = (ushort*)alloc(256 * D * 2);
  ushort* BpL1  = (ushort*)alloc(256 * D * 2);
  ushort* BpL2  = (ushort*)alloc(256 * D * 2);
  ushort* BpP0  = (ushort*)alloc(128 * D * 2);
  ushort* BpP1  = (ushort*)alloc(128 * D * 2);
  int*    deg    = (int*)alloc((size_t)N * 4);
  int*    rowptr = (int*)alloc((size_t)(N + 1) * 4);
  int*    cursor = (int*)alloc((size_t)N * 4);
  int*    part   = (int*)alloc(4096);
  int*    csrc   = (int*)alloc((size_t)E * 4);
  (void)ws_size; (void)n_in; (void)out_size;

  // --- CSR build (once; shared by all 3 layers) ---
  hipMemsetAsync(deg, 0, (size_t)N * 4, stream);
  int eb = (E + 255) / 256;
  k_degree<<<eb, 256, 0, stream>>>(dst, E, deg);
  int nb = (N + SCAN_CHUNK - 1) / SCAN_CHUNK;
  k_scan_partial<<<nb, SCAN_T, 0, stream>>>(deg, N, part);
  k_scan_part_ex<<<1, 1024, 0, stream>>>(part, nb);
  k_scan_final<<<nb, SCAN_T, 0, stream>>>(deg, N, part, rowptr, E);
  hipMemcpyAsync(cursor, rowptr, (size_t)N * 4, hipMemcpyDeviceToDevice, stream);
  k_fill<<<eb, 256, 0, stream>>>(src, dst, E, cursor, csrc);

  // --- conversions / weight packing ---
  int n8 = N * D / 8;
  k_conv_bf16<<<(n8 + 255) / 256, 256, 0, stream>>>(x, xb, n8);
  k_packW<<<(8 * 4096 + 255) / 256, 256, 0, stream>>>(Ws0, Wn0, BpL0, 8);
  k_packW<<<(8 * 4096 + 255) / 256, 256, 0, stream>>>(Ws1, Wn1, BpL1, 8);
  k_packW<<<(8 * 4096 + 255) / 256, 256, 0, stream>>>(Ws2, Wn2, BpL2, 8);
  k_packW<<<(4 * 4096 + 255) / 256, 256, 0, stream>>>(Wp0, Wp0, BpP0, 4);
  k_packW<<<(4 * 4096 + 255) / 256, 256, 0, stream>>>(Wp1, Wp1, BpP1, 4);

  int aggb = (int)(((size_t)N * 64 + 255) / 256);
  int gemb = (N + 63) / 64;
  // layer 0
  k_aggregate_b<<<aggb, 256, 0, stream>>>(xb, rowptr, csrc, hn, N);
  k_gemm_mfma<<<gemb, 256, 0, stream>>>(xb, hn, BpL0, b0, h1, N, 1);
  // layer 1
  k_aggregate_b<<<aggb, 256, 0, stream>>>(h1, rowptr, csrc, hn, N);
  k_gemm_mfma<<<gemb, 256, 0, stream>>>(h1, hn, BpL1, b1, h2, N, 1);
  // layer 2 (no relu) -> reuse xb as h3
  k_aggregate_b<<<aggb, 256, 0, stream>>>(h2, rowptr, csrc, hn, N);
  k_gemm_mfma<<<gemb, 256, 0, stream>>>(h2, hn, BpL2, b2, xb, N, 0);
  // predictor (pos then neg)
  int pb = (P + 63) / 64;
  k_predict_mfma<<<pb, 256, 0, stream>>>(xb, pos_src, pos_dst, BpP0, bp0, BpP1, bp1, Wp2, bp2, outp, P);
  k_predict_mfma<<<pb, 256, 0, stream>>>(xb, neg_src, neg_dst, BpP0, bp0, BpP1, bp1, Wp2, bp2, outp + P, P);
}

// Round 3
// 500.187 us; speedup vs baseline: 1.9414x; 1.2669x over previous
//
#include <hip/hip_runtime.h>
#include <cstdint>
#include <cstddef>
#include <cmath>

#define D 128

typedef short bf16x8 __attribute__((ext_vector_type(8)));
typedef float f32x4 __attribute__((ext_vector_type(4)));

__device__ __forceinline__ ushort f2b(float f) {
  uint x = __float_as_uint(f);
  uint r = ((x >> 16) & 1u) + 0x7fffu;   // round-to-nearest-even
  return (ushort)((x + r) >> 16);
}
__device__ __forceinline__ float b2f(ushort u) {
  return __uint_as_float(((uint)u) << 16);
}

// ======================= CSR build =======================
__global__ void k_degree(const int* __restrict__ dst, int E, int* __restrict__ deg) {
  int e = blockIdx.x * blockDim.x + threadIdx.x;
  if (e < E) atomicAdd(&deg[dst[e]], 1);
}

#define SCAN_T 256
#define SCAN_E 4
#define SCAN_CHUNK (SCAN_T * SCAN_E)

__global__ void k_scan_partial(const int* __restrict__ deg, int n, int* __restrict__ part) {
  __shared__ int s[SCAN_T];
  int base = blockIdx.x * SCAN_CHUNK;
  int sum = 0;
  for (int i = 0; i < SCAN_E; ++i) {
    int idx = base + (int)threadIdx.x * SCAN_E + i;
    if (idx < n) sum += deg[idx];
  }
  s[threadIdx.x] = sum; __syncthreads();
  for (int ofs = SCAN_T / 2; ofs > 0; ofs >>= 1) {
    if ((int)threadIdx.x < ofs) s[threadIdx.x] += s[threadIdx.x + ofs];
    __syncthreads();
  }
  if (threadIdx.x == 0) part[blockIdx.x] = s[0];
}

__global__ void k_scan_part_ex(int* __restrict__ part, int nb) {
  __shared__ int s[1024];
  int v = ((int)threadIdx.x < nb) ? part[threadIdx.x] : 0;
  s[threadIdx.x] = v; __syncthreads();
  for (int ofs = 1; ofs < 1024; ofs <<= 1) {
    int t = ((int)threadIdx.x >= ofs) ? s[threadIdx.x - ofs] : 0;
    __syncthreads();
    s[threadIdx.x] += t;
    __syncthreads();
  }
  if ((int)threadIdx.x < nb) part[threadIdx.x] = s[threadIdx.x] - v;  // exclusive
}

__global__ void k_scan_final(const int* __restrict__ deg, int n, const int* __restrict__ part,
                             int* __restrict__ rowptr, int E) {
  __shared__ int s[SCAN_T];
  int base = blockIdx.x * SCAN_CHUNK;
  int v[SCAN_E]; int local = 0;
  for (int i = 0; i < SCAN_E; ++i) {
    int idx = base + (int)threadIdx.x * SCAN_E + i;
    v[i] = (idx < n) ? deg[idx] : 0;
    local += v[i];
  }
  s[threadIdx.x] = local; __syncthreads();
  for (int ofs = 1; ofs < SCAN_T; ofs <<= 1) {
    int t = ((int)threadIdx.x >= ofs) ? s[threadIdx.x - ofs] : 0;
    __syncthreads();
    s[threadIdx.x] += t;
    __syncthreads();
  }
  int run = part[blockIdx.x] + s[threadIdx.x] - local;  // exclusive prefix
  for (int i = 0; i < SCAN_E; ++i) {
    int idx = base + (int)threadIdx.x * SCAN_E + i;
    if (idx < n) rowptr[idx] = run;
    run += v[i];
  }
  if (blockIdx.x == 0 && threadIdx.x == 0) rowptr[n] = E;
}

__global__ void k_fill(const int* __restrict__ src, const int* __restrict__ dst, int E,
                       int* __restrict__ cursor, int* __restrict__ csrc) {
  int e = blockIdx.x * blockDim.x + threadIdx.x;
  if (e < E) {
    int p = atomicAdd(&cursor[dst[e]], 1);
    csrc[p] = src[e];
  }
}

// ======================= fp32 -> bf16 convert =======================
__global__ void k_conv_bf16(const float* __restrict__ in, ushort* __restrict__ out, int n8) {
  int i = blockIdx.x * 256 + threadIdx.x;
  if (i >= n8) return;
  float4 a = ((const float4*)in)[i * 2];
  float4 b = ((const float4*)in)[i * 2 + 1];
  ushort4 o0 = {f2b(a.x), f2b(a.y), f2b(a.z), f2b(a.w)};
  ushort4 o1 = {f2b(b.x), f2b(b.y), f2b(b.z), f2b(b.w)};
  ((ushort4*)out)[i * 2] = o0;
  ((ushort4*)out)[i * 2 + 1] = o1;
}

// ======================= pack weights to B-fragment order =======================
// packed[((ks*8 + t)*64 + lane)*8 + j] = W[ks*32 + (lane>>4)*8 + j][t*16 + (lane&15)]
// virtual W: k<128 -> W0[k][n], k>=128 -> W1[k-128][n]
__global__ void k_packW(const float* __restrict__ W0, const float* __restrict__ W1,
                        ushort* __restrict__ out, int ksteps) {
  int o = blockIdx.x * 256 + threadIdx.x;
  int total = ksteps * 4096;
  if (o >= total) return;
  int j = o & 7, lane = (o >> 3) & 63, t = (o >> 9) & 7, ks = o >> 12;
  int k = ks * 32 + ((lane >> 4) * 8) + j;
  int n = t * 16 + (lane & 15);
  const float* W = (k < 128) ? W0 : W1;
  int kk = (k < 128) ? k : k - 128;
  out[o] = f2b(W[(size_t)kk * D + n]);
}

// ======================= mean aggregation ================
// wave per node; 16-lane group per edge (4 edges/iter, x2 unroll -> 8 rows in flight)
__global__ __launch_bounds__(256) void k_aggregate_b(const ushort* __restrict__ h,
    const int* __restrict__ rowptr, const int* __restrict__ csrc,
    ushort* __restrict__ hn, int N) {
  int wid = (int)((blockIdx.x * (size_t)blockDim.x + threadIdx.x) >> 6);
  int lane = threadIdx.x & 63;
  if (wid >= N) return;
  int grp = lane >> 4, sub = lane & 15;
  int beg = rowptr[wid], end = rowptr[wid + 1];
  const ushort* hb = h + sub * 8;
  float f[8] = {0.f, 0.f, 0.f, 0.f, 0.f, 0.f, 0.f, 0.f};
  int i = beg + grp;
  for (; i + 4 < end; i += 8) {
    int s0 = csrc[i], s1 = csrc[i + 4];
    bf16x8 v0 = *(const bf16x8*)(hb + (size_t)s0 * D);
    bf16x8 v1 = *(const bf16x8*)(hb + (size_t)s1 * D);
    #pragma unroll
    for (int j = 0; j < 8; ++j)
      f[j] += b2f((ushort)v0[j]) + b2f((ushort)v1[j]);
  }
  if (i < end) {
    int s0 = csrc[i];
    bf16x8 v0 = *(const bf16x8*)(hb + (size_t)s0 * D);
    #pragma unroll
    for (int j = 0; j < 8; ++j) f[j] += b2f((ushort)v0[j]);
  }
  // reduce the 4 edge-groups
  #pragma unroll
  for (int j = 0; j < 8; ++j) {
    f[j] += __shfl_xor(f[j], 16);
    f[j] += __shfl_xor(f[j], 32);
  }
  if (grp == 0) {
    float inv = (end > beg) ? (1.0f / (float)(end - beg)) : 0.0f;
    bf16x8 o;
    #pragma unroll
    for (int j = 0; j < 8; ++j) o[j] = (short)f2b(f[j] * inv);
    *(bf16x8*)(hn + (size_t)wid * D + sub * 8) = o;
  }
}

// ======================= SAGE layer GEMM (MFMA, no LDS) =======================
// out[r][c] = act( sum_k A[r][k] Ws[k][c] + An[r][k] Wn[k][c] + b[c] )
// virtual K=256: ks 0..3 from A/Ws, ks 4..7 from An/Wn (baked into packed Bp).
__global__ __launch_bounds__(256) void k_gemm_mfma(
    const ushort* __restrict__ A, const ushort* __restrict__ An,
    const ushort* __restrict__ Bp, const float* __restrict__ bias,
    ushort* __restrict__ out, int N, int do_relu) {
  int tid = threadIdx.x;
  int wave = tid >> 6, lane = tid & 63;
  int m = lane & 15, kg = lane >> 4;
  int row0 = blockIdx.x * 64 + wave * 16;
  int ar = row0 + m; if (ar >= N) ar = N - 1;   // clamp reads; stores guarded
  const ushort* a_self = A  + (size_t)ar * D + kg * 8;
  const ushort* a_nei  = An + (size_t)ar * D + kg * 8;
  f32x4 acc[8];
  #pragma unroll
  for (int t = 0; t < 8; ++t) acc[t] = f32x4{0.f, 0.f, 0.f, 0.f};
  #pragma unroll
  for (int ks = 0; ks < 8; ++ks) {
    const ushort* ap = (ks < 4) ? a_self : a_nei;
    bf16x8 af = *(const bf16x8*)(ap + (ks & 3) * 32);
    const ushort* bb = Bp + (size_t)ks * 4096 + lane * 8;
    #pragma unroll
    for (int t = 0; t < 8; ++t)
      acc[t] = __builtin_amdgcn_mfma_f32_16x16x32_bf16(af, *(const bf16x8*)(bb + t * 512), acc[t], 0, 0, 0);
  }
  #pragma unroll
  for (int t = 0; t < 8; ++t) {
    int c = t * 16 + m;
    float bv = bias[c];
    #pragma unroll
    for (int i = 0; i < 4; ++i) {
      int r = row0 + kg * 4 + i;
      float v = acc[t][i] + bv;
      if (do_relu) v = fmaxf(v, 0.f);
      if (r < N) out[(size_t)r * D + c] = f2b(v);
    }
  }
}

// ======================= fused predictor MLP (MFMA) =======================
__global__ __launch_bounds__(256) void k_predict_mfma(
    const ushort* __restrict__ h, const int* __restrict__ sidx, const int* __restrict__ didx,
    const ushort* __restrict__ Bp0, const float* __restrict__ bp0,
    const ushort* __restrict__ Bp1, const float* __restrict__ bp1,
    const float* __restrict__ Wp2, const float* __restrict__ bp2,
    float* __restrict__ outp, int P) {
  __shared__ __align__(16) ushort z1p[4][2048];  // per-wave A-frag-packed z1 (4 KB/wave)
  int tid = threadIdx.x;
  int wave = tid >> 6, lane = tid & 63;
  int m = lane & 15, kg = lane >> 4;
  int pair0 = blockIdx.x * 64 + wave * 16;
  int prow = pair0 + m; int pr = (prow < P) ? prow : P - 1;
  int si = sidx[pr], di = didx[pr];
  const ushort* hs = h + (size_t)si * D + kg * 8;
  const ushort* hd = h + (size_t)di * D + kg * 8;
  f32x4 acc[8];
  #pragma unroll
  for (int t = 0; t < 8; ++t) acc[t] = f32x4{0.f, 0.f, 0.f, 0.f};
  // ---- GEMM1: z = hs*hd ; acc = z @ Wp0 ----
  #pragma unroll
  for (int ks = 0; ks < 4; ++ks) {
    bf16x8 as8 = *(const bf16x8*)(hs + ks * 32);
    bf16x8 ad8 = *(const bf16x8*)(hd + ks * 32);
    bf16x8 af;
    #pragma unroll
    for (int j = 0; j < 8; ++j) {
      float p = b2f((ushort)as8[j]) * b2f((ushort)ad8[j]);
      af[j] = (short)f2b(p);
    }
    const ushort* bb = Bp0 + (size_t)ks * 4096 + lane * 8;
    #pragma unroll
    for (int t = 0; t < 8; ++t)
      acc[t] = __builtin_amdgcn_mfma_f32_16x16x32_bf16(af, *(const bf16x8*)(bb + t * 512), acc[t], 0, 0, 0);
  }
  // ---- epilogue1: relu(acc + bp0) -> LDS in GEMM2 A-fragment packed order ----
  ushort* zp = &z1p[wave][0];
  #pragma unroll
  for (int t = 0; t < 8; ++t) {
    int c = t * 16 + m;
    float bv = bp0[c];
    int ks2 = c >> 5, kg2 = (c >> 3) & 3, j2 = c & 7;
    #pragma unroll
    for (int i = 0; i < 4; ++i) {
      float v = fmaxf(acc[t][i] + bv, 0.f);
      int l2 = kg2 * 16 + kg * 4 + i;     // consumer lane
      zp[(ks2 * 64 + l2) * 8 + j2] = f2b(v);
    }
  }
  __syncthreads();
  // ---- GEMM2: acc = z1 @ Wp1 ----
  #pragma unroll
  for (int t = 0; t < 8; ++t) acc[t] = f32x4{0.f, 0.f, 0.f, 0.f};
  #pragma unroll
  for (int ks = 0; ks < 4; ++ks) {
    bf16x8 af = *(const bf16x8*)(zp + (ks * 64 + lane) * 8);
    const ushort* bb = Bp1 + (size_t)ks * 4096 + lane * 8;
    #pragma unroll
    for (int t = 0; t < 8; ++t)
      acc[t] = __builtin_amdgcn_mfma_f32_16x16x32_bf16(af, *(const bf16x8*)(bb + t * 512), acc[t], 0, 0, 0);
  }
  // ---- final: z2 = relu(acc + bp1); logits = z2 @ Wp2 + bp2; sigmoid ----
  float p0[4] = {0.f, 0.f, 0.f, 0.f}, p1[4] = {0.f, 0.f, 0.f, 0.f};
  #pragma unroll
  for (int t = 0; t < 8; ++t) {
    int c = t * 16 + m;
    float bv = bp1[c];
    float wa = Wp2[(size_t)c * 2], wb = Wp2[(size_t)c * 2 + 1];
    #pragma unroll
    for (int i = 0; i < 4; ++i) {
      float z = fmaxf(acc[t][i] + bv, 0.f);
      p0[i] += z * wa;
      p1[i] += z * wb;
    }
  }
  #pragma unroll
  for (int msk = 1; msk <= 8; msk <<= 1) {
    #pragma unroll
    for (int i = 0; i < 4; ++i) {
      p0[i] += __shfl_xor(p0[i], msk);
      p1[i] += __shfl_xor(p1[i], msk);
    }
  }
  if (m == 0) {
    float c0 = bp2[0], c1 = bp2[1];
    #pragma unroll
    for (int i = 0; i < 4; ++i) {
      int r = pair0 + kg * 4 + i;
      if (r < P) {
        float l0 = p0[i] + c0, l1 = p1[i] + c1;
        outp[r] = 1.0f / (1.0f + expf(l0 - l1));
      }
    }
  }
}

// ======================= launch =======================
extern "C" void kernel_launch(void* const* d_in, const int* in_sizes, int n_in,
                              void* d_out, int out_size, void* d_ws, size_t ws_size,
                              hipStream_t stream) {
  const float* x       = (const float*)d_in[0];
  const int*   src     = (const int*)d_in[1];
  const int*   dst     = (const int*)d_in[2];
  const int*   pos_src = (const int*)d_in[3];
  const int*   pos_dst = (const int*)d_in[4];
  const int*   neg_src = (const int*)d_in[5];
  const int*   neg_dst = (const int*)d_in[6];
  const float* Ws0 = (const float*)d_in[7],  *Wn0 = (const float*)d_in[8],  *b0 = (const float*)d_in[9];
  const float* Ws1 = (const float*)d_in[10], *Wn1 = (const float*)d_in[11], *b1 = (const float*)d_in[12];
  const float* Ws2 = (const float*)d_in[13], *Wn2 = (const float*)d_in[14], *b2 = (const float*)d_in[15];
  const float* Wp0 = (const float*)d_in[16], *bp0 = (const float*)d_in[17];
  const float* Wp1 = (const float*)d_in[18], *bp1 = (const float*)d_in[19];
  const float* Wp2 = (const float*)d_in[20], *bp2 = (const float*)d_in[21];
  const int N = in_sizes[0] / D;
  const int E = in_sizes[1];
  const int P = in_sizes[3];
  float* outp = (float*)d_out;

  char* ws = (char*)d_ws;
  size_t off = 0;
  auto alloc = [&](size_t bytes) -> void* {
    void* p = ws + off;
    off += (bytes + 255) & ~(size_t)255;
    return p;
  };
  ushort* xb    = (ushort*)alloc((size_t)N * D * 2);
  ushort* h1    = (ushort*)alloc((size_t)N * D * 2);
  ushort* h2    = (ushort*)alloc((size_t)N * D * 2);
  ushort* hn    = (ushort*)alloc((size_t)N * D * 2);
  ushort* BpL0  = (ushort*)alloc(256 * D * 2);
  ushort* BpL1  = (ushort*)alloc(256 * D * 2);
  ushort* BpL2  = (ushort*)alloc(256 * D * 2);
  ushort* BpP0  = (ushort*)alloc(128 * D * 2);
  ushort* BpP1  = (ushort*)alloc(128 * D * 2);
  int*    deg    = (int*)alloc((size_t)N * 4);
  int*    rowptr = (int*)alloc((size_t)(N + 1) * 4);
  int*    cursor = (int*)alloc((size_t)N * 4);
  int*    part   = (int*)alloc(4096);
  int*    csrc   = (int*)alloc((size_t)E * 4);
  (void)ws_size; (void)n_in; (void)out_size;

  // --- CSR build (once; shared by all 3 layers) ---
  hipMemsetAsync(deg, 0, (size_t)N * 4, stream);
  int eb = (E + 255) / 256;
  k_degree<<<eb, 256, 0, stream>>>(dst, E, deg);
  int nb = (N + SCAN_CHUNK - 1) / SCAN_CHUNK;
  k_scan_partial<<<nb, SCAN_T, 0, stream>>>(deg, N, part);
  k_scan_part_ex<<<1, 1024, 0, stream>>>(part, nb);
  k_scan_final<<<nb, SCAN_T, 0, stream>>>(deg, N, part, rowptr, E);
  hipMemcpyAsync(cursor, rowptr, (size_t)N * 4, hipMemcpyDeviceToDevice, stream);
  k_fill<<<eb, 256, 0, stream>>>(src, dst, E, cursor, csrc);

  // --- conversions / weight packing ---
  int n8 = N * D / 8;
  k_conv_bf16<<<(n8 + 255) / 256, 256, 0, stream>>>(x, xb, n8);
  k_packW<<<(8 * 4096 + 255) / 256, 256, 0, stream>>>(Ws0, Wn0, BpL0, 8);
  k_packW<<<(8 * 4096 + 255) / 256, 256, 0, stream>>>(Ws1, Wn1, BpL1, 8);
  k_packW<<<(8 * 4096 + 255) / 256, 256, 0, stream>>>(Ws2, Wn2, BpL2, 8);
  k_packW<<<(4 * 4096 + 255) / 256, 256, 0, stream>>>(Wp0, Wp0, BpP0, 4);
  k_packW<<<(4 * 4096 + 255) / 256, 256, 0, stream>>>(Wp1, Wp1, BpP1, 4);

  int aggb = (int)(((size_t)N * 64 + 255) / 256);
  int gemb = (N + 63) / 64;
  // layer 0
  k_aggregate_b<<<aggb, 256, 0, stream>>>(xb, rowptr, csrc, hn, N);
  k_gemm_mfma<<<gemb, 256, 0, stream>>>(xb, hn, BpL0, b0, h1, N, 1);
  // layer 1
  k_aggregate_b<<<aggb, 256, 0, stream>>>(h1, rowptr, csrc, hn, N);
  k_gemm_mfma<<<gemb, 256, 0, stream>>>(h1, hn, BpL1, b1, h2, N, 1);
  // layer 2 (no relu) -> reuse xb as h3
  k_aggregate_b<<<aggb, 256, 0, stream>>>(h2, rowptr, csrc, hn, N);
  k_gemm_mfma<<<gemb, 256, 0, stream>>>(h2, hn, BpL2, b2, xb, N, 0);
  // predictor (pos then neg)
  int pb = (P + 63) / 64;
  k_predict_mfma<<<pb, 256, 0, stream>>>(xb, pos_src, pos_dst, BpP0, bp0, BpP1, bp1, Wp2, bp2, outp, P);
  k_predict_mfma<<<pb, 256, 0, stream>>>(xb, neg_src, neg_dst, BpP0, bp0, BpP1, bp1, Wp2, bp2, outp + P, P);
}

// Round 4
// 498.038 us; speedup vs baseline: 1.9497x; 1.0043x over previous
//
#include <hip/hip_runtime.h>
#include <cstdint>
#include <cstddef>
#include <cmath>

#define D 128

typedef short bf16x8 __attribute__((ext_vector_type(8)));
typedef float f32x4 __attribute__((ext_vector_type(4)));

__device__ __forceinline__ ushort f2b(float f) {
  uint x = __float_as_uint(f);
  uint r = ((x >> 16) & 1u) + 0x7fffu;   // round-to-nearest-even
  return (ushort)((x + r) >> 16);
}
__device__ __forceinline__ float b2f(ushort u) {
  return __uint_as_float(((uint)u) << 16);
}

// ======================= CSR build (XCD-partitioned) =======================
// part = blockIdx & 7 (round-robin XCD heuristic; correctness independent of
// the mapping). Each part only commits edges whose dst falls in its 1/8 node
// range -> all writers of a deg/cursor/csrc cache line live on one XCD, so
// partial lines accumulate in local L2 and write back full (kills the 16x
// write amplification seen as WRITE_SIZE=53MB for a 3.2MB csrc array).
__global__ __launch_bounds__(256) void k_degree_p(const int* __restrict__ dst, int E,
    int* __restrict__ deg, float scale, int CE) {
  int part = blockIdx.x & 7, chunk = blockIdx.x >> 3;
  long base = (long)chunk * CE;
  for (int i = threadIdx.x; i < CE; i += 256) {
    long e = base + i;
    if (e < E) {
      int d = dst[e];
      int p = (int)((float)d * scale); if (p > 7) p = 7;
      if (p == part) atomicAdd(&deg[d], 1);
    }
  }
}

__global__ __launch_bounds__(256) void k_fill_p(const int* __restrict__ src,
    const int* __restrict__ dst, int E, int* __restrict__ cursor,
    int* __restrict__ csrc, float scale, int CE) {
  int part = blockIdx.x & 7, chunk = blockIdx.x >> 3;
  long base = (long)chunk * CE;
  for (int i = threadIdx.x; i < CE; i += 256) {
    long e = base + i;
    if (e < E) {
      int d = dst[e];
      int p = (int)((float)d * scale); if (p > 7) p = 7;
      if (p == part) {
        int s = src[e];
        int pos = atomicAdd(&cursor[d], 1);
        csrc[pos] = s;
      }
    }
  }
}

#define SCAN_T 256
#define SCAN_E 4
#define SCAN_CHUNK (SCAN_T * SCAN_E)

__global__ void k_scan_partial(const int* __restrict__ deg, int n, int* __restrict__ part) {
  __shared__ int s[SCAN_T];
  int base = blockIdx.x * SCAN_CHUNK;
  int sum = 0;
  for (int i = 0; i < SCAN_E; ++i) {
    int idx = base + (int)threadIdx.x * SCAN_E + i;
    if (idx < n) sum += deg[idx];
  }
  s[threadIdx.x] = sum; __syncthreads();
  for (int ofs = SCAN_T / 2; ofs > 0; ofs >>= 1) {
    if ((int)threadIdx.x < ofs) s[threadIdx.x] += s[threadIdx.x + ofs];
    __syncthreads();
  }
  if (threadIdx.x == 0) part[blockIdx.x] = s[0];
}

__global__ void k_scan_part_ex(int* __restrict__ part, int nb) {
  __shared__ int s[1024];
  int v = ((int)threadIdx.x < nb) ? part[threadIdx.x] : 0;
  s[threadIdx.x] = v; __syncthreads();
  for (int ofs = 1; ofs < 1024; ofs <<= 1) {
    int t = ((int)threadIdx.x >= ofs) ? s[threadIdx.x - ofs] : 0;
    __syncthreads();
    s[threadIdx.x] += t;
    __syncthreads();
  }
  if ((int)threadIdx.x < nb) part[threadIdx.x] = s[threadIdx.x] - v;  // exclusive
}

__global__ void k_scan_final(const int* __restrict__ deg, int n, const int* __restrict__ part,
                             int* __restrict__ rowptr, int E) {
  __shared__ int s[SCAN_T];
  int base = blockIdx.x * SCAN_CHUNK;
  int v[SCAN_E]; int local = 0;
  for (int i = 0; i < SCAN_E; ++i) {
    int idx = base + (int)threadIdx.x * SCAN_E + i;
    v[i] = (idx < n) ? deg[idx] : 0;
    local += v[i];
  }
  s[threadIdx.x] = local; __syncthreads();
  for (int ofs = 1; ofs < SCAN_T; ofs <<= 1) {
    int t = ((int)threadIdx.x >= ofs) ? s[threadIdx.x - ofs] : 0;
    __syncthreads();
    s[threadIdx.x] += t;
    __syncthreads();
  }
  int run = part[blockIdx.x] + s[threadIdx.x] - local;  // exclusive prefix
  for (int i = 0; i < SCAN_E; ++i) {
    int idx = base + (int)threadIdx.x * SCAN_E + i;
    if (idx < n) rowptr[idx] = run;
    run += v[i];
  }
  if (blockIdx.x == 0 && threadIdx.x == 0) rowptr[n] = E;
}

// ======================= fp32 -> bf16 convert =======================
__global__ void k_conv_bf16(const float* __restrict__ in, ushort* __restrict__ out, int n8) {
  int i = blockIdx.x * 256 + threadIdx.x;
  if (i >= n8) return;
  float4 a = ((const float4*)in)[i * 2];
  float4 b = ((const float4*)in)[i * 2 + 1];
  ushort4 o0 = {f2b(a.x), f2b(a.y), f2b(a.z), f2b(a.w)};
  ushort4 o1 = {f2b(b.x), f2b(b.y), f2b(b.z), f2b(b.w)};
  ((ushort4*)out)[i * 2] = o0;
  ((ushort4*)out)[i * 2 + 1] = o1;
}

// ======================= pack ALL weights to B-fragment order ==================
// packed[((ks*8 + t)*64 + lane)*8 + j] = W[ks*32 + (lane>>4)*8 + j][t*16 + (lane&15)]
// virtual W: k<128 -> W0[k][n], k>=128 -> W1[k-128][n]
__global__ void k_pack_all(
    const float* __restrict__ Ws0, const float* __restrict__ Wn0,
    const float* __restrict__ Ws1, const float* __restrict__ Wn1,
    const float* __restrict__ Ws2, const float* __restrict__ Wn2,
    const float* __restrict__ Wp0, const float* __restrict__ Wp1,
    ushort* __restrict__ BpL0, ushort* __restrict__ BpL1, ushort* __restrict__ BpL2,
    ushort* __restrict__ BpP0, ushort* __restrict__ BpP1) {
  int o = blockIdx.x * 256 + threadIdx.x;   // total 131072
  const float *W0, *W1; ushort* out; int rel;
  if (o < 32768)       { W0 = Ws0; W1 = Wn0; out = BpL0; rel = o; }
  else if (o < 65536)  { W0 = Ws1; W1 = Wn1; out = BpL1; rel = o - 32768; }
  else if (o < 98304)  { W0 = Ws2; W1 = Wn2; out = BpL2; rel = o - 65536; }
  else if (o < 114688) { W0 = Wp0; W1 = Wp0; out = BpP0; rel = o - 98304; }
  else                 { W0 = Wp1; W1 = Wp1; out = BpP1; rel = o - 114688; }
  int j = rel & 7, lane = (rel >> 3) & 63, t = (rel >> 9) & 7, ks = rel >> 12;
  int k = ks * 32 + ((lane >> 4) * 8) + j;
  int n = t * 16 + (lane & 15);
  const float* W = (k < 128) ? W0 : W1;
  int kk = (k < 128) ? k : k - 128;
  out[rel] = f2b(W[(size_t)kk * D + n]);
}

// ======================= fused aggregate + SAGE GEMM =======================
// Block = 64 rows (4 waves x 16). Each wave gathers the neighbor-mean for its
// 16 MFMA rows into LDS (stride 136 ushort -> uniform 8-way b128 = LDS floor),
// then runs the K=256 MFMA with self-frags from global and neighbor-frags
// from LDS. Kills the hn global round-trip.
#define SMS 136
__global__ __launch_bounds__(256) void k_sage_fused(
    const ushort* __restrict__ A, const int* __restrict__ rowptr,
    const int* __restrict__ csrc, const ushort* __restrict__ Bp,
    const float* __restrict__ bias, ushort* __restrict__ out, int N, int do_relu) {
  __shared__ __align__(16) ushort smean[4][16][SMS];
  int tid = threadIdx.x, wave = tid >> 6, lane = tid & 63;
  int m = lane & 15, kg = lane >> 4;    // MFMA roles; gather: grp=kg, sub=m
  int row0 = blockIdx.x * 64 + wave * 16;
  // preload rowptr[row0 .. row0+16] once, broadcast via shfl
  int rp = 0;
  { int idx = row0 + lane; if (lane < 17 && idx <= N) rp = rowptr[idx]; }
  const ushort* hb = A + m * 8;   // sub==m: element chunk
  // ---- gather phase ----
  for (int t = 0; t < 16; ++t) {
    int beg = __shfl(rp, t), end = __shfl(rp, t + 1);
    if (end < beg) end = beg;   // clamped-tail safety
    float f[8] = {0.f, 0.f, 0.f, 0.f, 0.f, 0.f, 0.f, 0.f};
    int i = beg + kg;
    for (; i + 4 < end; i += 8) {
      int s0 = csrc[i], s1 = csrc[i + 4];
      bf16x8 v0 = *(const bf16x8*)(hb + (size_t)s0 * D);
      bf16x8 v1 = *(const bf16x8*)(hb + (size_t)s1 * D);
      #pragma unroll
      for (int j = 0; j < 8; ++j)
        f[j] += b2f((ushort)v0[j]) + b2f((ushort)v1[j]);
    }
    if (i < end) {
      int s0 = csrc[i];
      bf16x8 v0 = *(const bf16x8*)(hb + (size_t)s0 * D);
      #pragma unroll
      for (int j = 0; j < 8; ++j) f[j] += b2f((ushort)v0[j]);
    }
    #pragma unroll
    for (int j = 0; j < 8; ++j) {
      f[j] += __shfl_xor(f[j], 16);
      f[j] += __shfl_xor(f[j], 32);
    }
    if (kg == 0) {
      float inv = (end > beg) ? (1.0f / (float)(end - beg)) : 0.0f;
      bf16x8 o;
      #pragma unroll
      for (int j = 0; j < 8; ++j) o[j] = (short)f2b(f[j] * inv);
      *(bf16x8*)&smean[wave][t][m * 8] = o;
    }
  }
  __syncthreads();
  // ---- MFMA phase ----
  int ar = row0 + m; if (ar >= N) ar = N - 1;   // clamp reads; stores guarded
  const ushort* a_self = A + (size_t)ar * D + kg * 8;
  f32x4 acc[8];
  #pragma unroll
  for (int t = 0; t < 8; ++t) acc[t] = f32x4{0.f, 0.f, 0.f, 0.f};
  #pragma unroll
  for (int ks = 0; ks < 8; ++ks) {
    bf16x8 af = (ks < 4) ? *(const bf16x8*)(a_self + ks * 32)
                         : *(const bf16x8*)&smean[wave][m][(ks - 4) * 32 + kg * 8];
    const ushort* bb = Bp + (size_t)ks * 4096 + lane * 8;
    #pragma unroll
    for (int t = 0; t < 8; ++t)
      acc[t] = __builtin_amdgcn_mfma_f32_16x16x32_bf16(af, *(const bf16x8*)(bb + t * 512), acc[t], 0, 0, 0);
  }
  #pragma unroll
  for (int t = 0; t < 8; ++t) {
    int c = t * 16 + m;
    float bv = bias[c];
    #pragma unroll
    for (int i = 0; i < 4; ++i) {
      int r = row0 + kg * 4 + i;
      float v = acc[t][i] + bv;
      if (do_relu) v = fmaxf(v, 0.f);
      if (r < N) out[(size_t)r * D + c] = f2b(v);
    }
  }
}

// ======================= fused predictor MLP (MFMA, pos+neg merged) ============
__global__ __launch_bounds__(256) void k_predict_mfma(
    const ushort* __restrict__ h,
    const int* __restrict__ ps, const int* __restrict__ pd,
    const int* __restrict__ ns, const int* __restrict__ nd,
    const ushort* __restrict__ Bp0, const float* __restrict__ bp0,
    const ushort* __restrict__ Bp1, const float* __restrict__ bp1,
    const float* __restrict__ Wp2, const float* __restrict__ bp2,
    float* __restrict__ outp, int P, int pb) {
  __shared__ __align__(16) ushort z1p[4][2048];  // per-wave A-frag-packed z1
  int bi = blockIdx.x;
  const int* sidx; const int* didx; float* op;
  if (bi >= pb) { sidx = ns; didx = nd; op = outp + P; bi -= pb; }
  else          { sidx = ps; didx = pd; op = outp; }
  int tid = threadIdx.x;
  int wave = tid >> 6, lane = tid & 63;
  int m = lane & 15, kg = lane >> 4;
  int pair0 = bi * 64 + wave * 16;
  int prow = pair0 + m; int pr = (prow < P) ? prow : P - 1;
  int si = sidx[pr], di = didx[pr];
  const ushort* hs = h + (size_t)si * D + kg * 8;
  const ushort* hd = h + (size_t)di * D + kg * 8;
  f32x4 acc[8];
  #pragma unroll
  for (int t = 0; t < 8; ++t) acc[t] = f32x4{0.f, 0.f, 0.f, 0.f};
  // ---- GEMM1: z = hs*hd ; acc = z @ Wp0 ----
  #pragma unroll
  for (int ks = 0; ks < 4; ++ks) {
    bf16x8 as8 = *(const bf16x8*)(hs + ks * 32);
    bf16x8 ad8 = *(const bf16x8*)(hd + ks * 32);
    bf16x8 af;
    #pragma unroll
    for (int j = 0; j < 8; ++j) {
      float p = b2f((ushort)as8[j]) * b2f((ushort)ad8[j]);
      af[j] = (short)f2b(p);
    }
    const ushort* bb = Bp0 + (size_t)ks * 4096 + lane * 8;
    #pragma unroll
    for (int t = 0; t < 8; ++t)
      acc[t] = __builtin_amdgcn_mfma_f32_16x16x32_bf16(af, *(const bf16x8*)(bb + t * 512), acc[t], 0, 0, 0);
  }
  // ---- epilogue1: relu(acc + bp0) -> LDS in GEMM2 A-fragment packed order ----
  ushort* zp = &z1p[wave][0];
  #pragma unroll
  for (int t = 0; t < 8; ++t) {
    int c = t * 16 + m;
    float bv = bp0[c];
    int ks2 = c >> 5, kg2 = (c >> 3) & 3, j2 = c & 7;
    #pragma unroll
    for (int i = 0; i < 4; ++i) {
      float v = fmaxf(acc[t][i] + bv, 0.f);
      int l2 = kg2 * 16 + kg * 4 + i;     // consumer lane
      zp[(ks2 * 64 + l2) * 8 + j2] = f2b(v);
    }
  }
  __syncthreads();
  // ---- GEMM2: acc = z1 @ Wp1 ----
  #pragma unroll
  for (int t = 0; t < 8; ++t) acc[t] = f32x4{0.f, 0.f, 0.f, 0.f};
  #pragma unroll
  for (int ks = 0; ks < 4; ++ks) {
    bf16x8 af = *(const bf16x8*)(zp + (ks * 64 + lane) * 8);
    const ushort* bb = Bp1 + (size_t)ks * 4096 + lane * 8;
    #pragma unroll
    for (int t = 0; t < 8; ++t)
      acc[t] = __builtin_amdgcn_mfma_f32_16x16x32_bf16(af, *(const bf16x8*)(bb + t * 512), acc[t], 0, 0, 0);
  }
  // ---- final: z2 = relu(acc + bp1); logits = z2 @ Wp2 + bp2; sigmoid ----
  float p0[4] = {0.f, 0.f, 0.f, 0.f}, p1[4] = {0.f, 0.f, 0.f, 0.f};
  #pragma unroll
  for (int t = 0; t < 8; ++t) {
    int c = t * 16 + m;
    float bv = bp1[c];
    float wa = Wp2[(size_t)c * 2], wb = Wp2[(size_t)c * 2 + 1];
    #pragma unroll
    for (int i = 0; i < 4; ++i) {
      float z = fmaxf(acc[t][i] + bv, 0.f);
      p0[i] += z * wa;
      p1[i] += z * wb;
    }
  }
  #pragma unroll
  for (int msk = 1; msk <= 8; msk <<= 1) {
    #pragma unroll
    for (int i = 0; i < 4; ++i) {
      p0[i] += __shfl_xor(p0[i], msk);
      p1[i] += __shfl_xor(p1[i], msk);
    }
  }
  if (m == 0) {
    float c0 = bp2[0], c1 = bp2[1];
    #pragma unroll
    for (int i = 0; i < 4; ++i) {
      int r = pair0 + kg * 4 + i;
      if (r < P) {
        float l0 = p0[i] + c0, l1 = p1[i] + c1;
        op[r] = 1.0f / (1.0f + expf(l0 - l1));
      }
    }
  }
}

// ======================= launch =======================
extern "C" void kernel_launch(void* const* d_in, const int* in_sizes, int n_in,
                              void* d_out, int out_size, void* d_ws, size_t ws_size,
                              hipStream_t stream) {
  const float* x       = (const float*)d_in[0];
  const int*   src     = (const int*)d_in[1];
  const int*   dst     = (const int*)d_in[2];
  const int*   pos_src = (const int*)d_in[3];
  const int*   pos_dst = (const int*)d_in[4];
  const int*   neg_src = (const int*)d_in[5];
  const int*   neg_dst = (const int*)d_in[6];
  const float* Ws0 = (const float*)d_in[7],  *Wn0 = (const float*)d_in[8],  *b0 = (const float*)d_in[9];
  const float* Ws1 = (const float*)d_in[10], *Wn1 = (const float*)d_in[11], *b1 = (const float*)d_in[12];
  const float* Ws2 = (const float*)d_in[13], *Wn2 = (const float*)d_in[14], *b2 = (const float*)d_in[15];
  const float* Wp0 = (const float*)d_in[16], *bp0 = (const float*)d_in[17];
  const float* Wp1 = (const float*)d_in[18], *bp1 = (const float*)d_in[19];
  const float* Wp2 = (const float*)d_in[20], *bp2 = (const float*)d_in[21];
  const int N = in_sizes[0] / D;
  const int E = in_sizes[1];
  const int P = in_sizes[3];
  float* outp = (float*)d_out;

  char* ws = (char*)d_ws;
  size_t off = 0;
  auto alloc = [&](size_t bytes) -> void* {
    void* p = ws + off;
    off += (bytes + 255) & ~(size_t)255;
    return p;
  };
  ushort* xb    = (ushort*)alloc((size_t)N * D * 2);
  ushort* h1    = (ushort*)alloc((size_t)N * D * 2);
  ushort* h2    = (ushort*)alloc((size_t)N * D * 2);
  ushort* BpL0  = (ushort*)alloc(256 * D * 2);
  ushort* BpL1  = (ushort*)alloc(256 * D * 2);
  ushort* BpL2  = (ushort*)alloc(256 * D * 2);
  ushort* BpP0  = (ushort*)alloc(128 * D * 2);
  ushort* BpP1  = (ushort*)alloc(128 * D * 2);
  int*    deg    = (int*)alloc((size_t)N * 4);
  int*    rowptr = (int*)alloc((size_t)(N + 1) * 4);
  int*    cursor = (int*)alloc((size_t)N * 4);
  int*    part   = (int*)alloc(4096);
  int*    csrc   = (int*)alloc((size_t)E * 4);
  (void)ws_size; (void)n_in; (void)out_size;

  const float pscale = 8.0f / (float)N;
  const int CB = 96;                           // blocks per part
  const int CE = (E + CB - 1) / CB;            // edges per chunk

  // --- CSR build (XCD-partitioned) ---
  hipMemsetAsync(deg, 0, (size_t)N * 4, stream);
  k_degree_p<<<8 * CB, 256, 0, stream>>>(dst, E, deg, pscale, CE);
  int nb = (N + SCAN_CHUNK - 1) / SCAN_CHUNK;
  k_scan_partial<<<nb, SCAN_T, 0, stream>>>(deg, N, part);
  k_scan_part_ex<<<1, 1024, 0, stream>>>(part, nb);
  k_scan_final<<<nb, SCAN_T, 0, stream>>>(deg, N, part, rowptr, E);
  hipMemcpyAsync(cursor, rowptr, (size_t)N * 4, hipMemcpyDeviceToDevice, stream);
  k_fill_p<<<8 * CB, 256, 0, stream>>>(src, dst, E, cursor, csrc, pscale, CE);

  // --- conversions / weight packing ---
  int n8 = N * D / 8;
  k_conv_bf16<<<(n8 + 255) / 256, 256, 0, stream>>>(x, xb, n8);
  k_pack_all<<<512, 256, 0, stream>>>(Ws0, Wn0, Ws1, Wn1, Ws2, Wn2, Wp0, Wp1,
                                      BpL0, BpL1, BpL2, BpP0, BpP1);

  int gemb = (N + 63) / 64;
  k_sage_fused<<<gemb, 256, 0, stream>>>(xb, rowptr, csrc, BpL0, b0, h1, N, 1);
  k_sage_fused<<<gemb, 256, 0, stream>>>(h1, rowptr, csrc, BpL1, b1, h2, N, 1);
  k_sage_fused<<<gemb, 256, 0, stream>>>(h2, rowptr, csrc, BpL2, b2, xb, N, 0);

  int pb = (P + 63) / 64;
  k_predict_mfma<<<2 * pb, 256, 0, stream>>>(xb, pos_src, pos_dst, neg_src, neg_dst,
                                             BpP0, bp0, BpP1, bp1, Wp2, bp2, outp, P, pb);
}

// Round 5
// 468.132 us; speedup vs baseline: 2.0743x; 1.0639x over previous
//
#include <hip/hip_runtime.h>
#include <cstdint>
#include <cstddef>
#include <cmath>

#define D 128

typedef short bf16x8 __attribute__((ext_vector_type(8)));
typedef float f32x4 __attribute__((ext_vector_type(4)));

__device__ __forceinline__ ushort f2b(float f) {
  uint x = __float_as_uint(f);
  uint r = ((x >> 16) & 1u) + 0x7fffu;   // round-to-nearest-even
  return (ushort)((x + r) >> 16);
}
__device__ __forceinline__ float b2f(ushort u) {
  return __uint_as_float(((uint)u) << 16);
}

// ======================= CSR build (XCD-partitioned) =======================
__global__ __launch_bounds__(256) void k_degree_p(const int* __restrict__ dst, int E,
    int* __restrict__ deg, float scale, int CE) {
  int part = blockIdx.x & 7, chunk = blockIdx.x >> 3;
  long base = (long)chunk * CE;
  for (int i = threadIdx.x; i < CE; i += 256) {
    long e = base + i;
    if (e < E) {
      int d = dst[e];
      int p = (int)((float)d * scale); if (p > 7) p = 7;
      if (p == part) atomicAdd(&deg[d], 1);
    }
  }
}

__global__ __launch_bounds__(256) void k_fill_p(const int* __restrict__ src,
    const int* __restrict__ dst, int E, int* __restrict__ cursor,
    int* __restrict__ csrc, float scale, int CE) {
  int part = blockIdx.x & 7, chunk = blockIdx.x >> 3;
  long base = (long)chunk * CE;
  for (int i = threadIdx.x; i < CE; i += 256) {
    long e = base + i;
    if (e < E) {
      int d = dst[e];
      int p = (int)((float)d * scale); if (p > 7) p = 7;
      if (p == part) {
        int s = src[e];
        int pos = atomicAdd(&cursor[d], 1);
        csrc[pos] = s;
      }
    }
  }
}

#define SCAN_T 256
#define SCAN_E 4
#define SCAN_CHUNK (SCAN_T * SCAN_E)

__global__ void k_scan_partial(const int* __restrict__ deg, int n, int* __restrict__ part) {
  __shared__ int s[SCAN_T];
  int base = blockIdx.x * SCAN_CHUNK;
  int sum = 0;
  for (int i = 0; i < SCAN_E; ++i) {
    int idx = base + (int)threadIdx.x * SCAN_E + i;
    if (idx < n) sum += deg[idx];
  }
  s[threadIdx.x] = sum; __syncthreads();
  for (int ofs = SCAN_T / 2; ofs > 0; ofs >>= 1) {
    if ((int)threadIdx.x < ofs) s[threadIdx.x] += s[threadIdx.x + ofs];
    __syncthreads();
  }
  if (threadIdx.x == 0) part[blockIdx.x] = s[0];
}

__global__ void k_scan_part_ex(int* __restrict__ part, int nb) {
  __shared__ int s[1024];
  int v = ((int)threadIdx.x < nb) ? part[threadIdx.x] : 0;
  s[threadIdx.x] = v; __syncthreads();
  for (int ofs = 1; ofs < 1024; ofs <<= 1) {
    int t = ((int)threadIdx.x >= ofs) ? s[threadIdx.x - ofs] : 0;
    __syncthreads();
    s[threadIdx.x] += t;
    __syncthreads();
  }
  if ((int)threadIdx.x < nb) part[threadIdx.x] = s[threadIdx.x] - v;  // exclusive
}

__global__ void k_scan_final(const int* __restrict__ deg, int n, const int* __restrict__ part,
                             int* __restrict__ rowptr, int* __restrict__ cursor, int E) {
  __shared__ int s[SCAN_T];
  int base = blockIdx.x * SCAN_CHUNK;
  int v[SCAN_E]; int local = 0;
  for (int i = 0; i < SCAN_E; ++i) {
    int idx = base + (int)threadIdx.x * SCAN_E + i;
    v[i] = (idx < n) ? deg[idx] : 0;
    local += v[i];
  }
  s[threadIdx.x] = local; __syncthreads();
  for (int ofs = 1; ofs < SCAN_T; ofs <<= 1) {
    int t = ((int)threadIdx.x >= ofs) ? s[threadIdx.x - ofs] : 0;
    __syncthreads();
    s[threadIdx.x] += t;
    __syncthreads();
  }
  int run = part[blockIdx.x] + s[threadIdx.x] - local;  // exclusive prefix
  for (int i = 0; i < SCAN_E; ++i) {
    int idx = base + (int)threadIdx.x * SCAN_E + i;
    if (idx < n) { rowptr[idx] = run; cursor[idx] = run; }
    run += v[i];
  }
  if (blockIdx.x == 0 && threadIdx.x == 0) rowptr[n] = E;
}

// ======================= fp32 -> bf16 convert =======================
__global__ void k_conv_bf16(const float* __restrict__ in, ushort* __restrict__ out, int n8) {
  int i = blockIdx.x * 256 + threadIdx.x;
  if (i >= n8) return;
  float4 a = ((const float4*)in)[i * 2];
  float4 b = ((const float4*)in)[i * 2 + 1];
  ushort4 o0 = {f2b(a.x), f2b(a.y), f2b(a.z), f2b(a.w)};
  ushort4 o1 = {f2b(b.x), f2b(b.y), f2b(b.z), f2b(b.w)};
  ((ushort4*)out)[i * 2] = o0;
  ((ushort4*)out)[i * 2 + 1] = o1;
}

// ======================= pack ALL weights to B-fragment order ==================
// packed[((ks*8 + t)*64 + lane)*8 + j] = W[ks*32 + (lane>>4)*8 + j][t*16 + (lane&15)]
// virtual W: k<128 -> W0[k][n], k>=128 -> W1[k-128][n]
__global__ void k_pack_all(
    const float* __restrict__ Ws0, const float* __restrict__ Wn0,
    const float* __restrict__ Ws1, const float* __restrict__ Wn1,
    const float* __restrict__ Ws2, const float* __restrict__ Wn2,
    const float* __restrict__ Wp0, const float* __restrict__ Wp1,
    ushort* __restrict__ BpL0, ushort* __restrict__ BpL1, ushort* __restrict__ BpL2,
    ushort* __restrict__ BpP0, ushort* __restrict__ BpP1) {
  int o = blockIdx.x * 256 + threadIdx.x;   // total 131072
  const float *W0, *W1; ushort* out; int rel;
  if (o < 32768)       { W0 = Ws0; W1 = Wn0; out = BpL0; rel = o; }
  else if (o < 65536)  { W0 = Ws1; W1 = Wn1; out = BpL1; rel = o - 32768; }
  else if (o < 98304)  { W0 = Ws2; W1 = Wn2; out = BpL2; rel = o - 65536; }
  else if (o < 114688) { W0 = Wp0; W1 = Wp0; out = BpP0; rel = o - 98304; }
  else                 { W0 = Wp1; W1 = Wp1; out = BpP1; rel = o - 114688; }
  int j = rel & 7, lane = (rel >> 3) & 63, t = (rel >> 9) & 7, ks = rel >> 12;
  int k = ks * 32 + ((lane >> 4) * 8) + j;
  int n = t * 16 + (lane & 15);
  const float* W = (k < 128) ? W0 : W1;
  int kk = (k < 128) ? k : k - 128;
  out[rel] = f2b(W[(size_t)kk * D + n]);
}

// ======================= fused aggregate + SAGE GEMM =======================
// Block = 64 rows (4 waves x 16 for MFMA). Gather: 16 independent 16-lane
// groups, each owning 4 whole nodes; per node the group walks the edge list
// 4-wide (4 independent b128 row loads in flight, no shuffles, no per-row
// sync) and writes the bf16 mean row to LDS. MFMA phase: self-frags from
// global, neighbor-frags from LDS.
#define SMS 136
__global__ __launch_bounds__(256) void k_sage_fused(
    const ushort* __restrict__ A, const int* __restrict__ rowptr,
    const int* __restrict__ csrc, const ushort* __restrict__ Bp,
    const float* __restrict__ bias, ushort* __restrict__ out, int N, int do_relu) {
  __shared__ __align__(16) ushort smean[64][SMS];
  int tid = threadIdx.x, wave = tid >> 6, lane = tid & 63;
  int m = lane & 15, kg = lane >> 4;        // MFMA roles
  int g = tid >> 4, sub = tid & 15;         // gather roles: 16 groups of 16
  const ushort* hb = A + sub * 8;
  // ---- gather phase: group g owns block-rows g*4 .. g*4+3 ----
  #pragma unroll
  for (int j = 0; j < 4; ++j) {
    int r = g * 4 + j;
    int node = blockIdx.x * 64 + r;
    int beg = 0, end = 0;
    if (node < N) { beg = rowptr[node]; end = rowptr[node + 1]; }
    float f[8] = {0.f, 0.f, 0.f, 0.f, 0.f, 0.f, 0.f, 0.f};
    int i = beg;
    for (; i + 3 < end; i += 4) {
      int s0 = csrc[i], s1 = csrc[i + 1], s2 = csrc[i + 2], s3 = csrc[i + 3];
      bf16x8 v0 = *(const bf16x8*)(hb + (size_t)s0 * D);
      bf16x8 v1 = *(const bf16x8*)(hb + (size_t)s1 * D);
      bf16x8 v2 = *(const bf16x8*)(hb + (size_t)s2 * D);
      bf16x8 v3 = *(const bf16x8*)(hb + (size_t)s3 * D);
      #pragma unroll
      for (int q = 0; q < 8; ++q)
        f[q] += (b2f((ushort)v0[q]) + b2f((ushort)v1[q]))
              + (b2f((ushort)v2[q]) + b2f((ushort)v3[q]));
    }
    for (; i < end; ++i) {
      int s0 = csrc[i];
      bf16x8 v0 = *(const bf16x8*)(hb + (size_t)s0 * D);
      #pragma unroll
      for (int q = 0; q < 8; ++q) f[q] += b2f((ushort)v0[q]);
    }
    float inv = (end > beg) ? (1.0f / (float)(end - beg)) : 0.0f;
    bf16x8 o;
    #pragma unroll
    for (int q = 0; q < 8; ++q) o[q] = (short)f2b(f[q] * inv);
    *(bf16x8*)&smean[r][sub * 8] = o;
  }
  __syncthreads();
  // ---- MFMA phase ----
  int row0 = blockIdx.x * 64 + wave * 16;
  int ar = row0 + m; if (ar >= N) ar = N - 1;   // clamp reads; stores guarded
  const ushort* a_self = A + (size_t)ar * D + kg * 8;
  f32x4 acc[8];
  #pragma unroll
  for (int t = 0; t < 8; ++t) acc[t] = f32x4{0.f, 0.f, 0.f, 0.f};
  #pragma unroll
  for (int ks = 0; ks < 8; ++ks) {
    bf16x8 af = (ks < 4) ? *(const bf16x8*)(a_self + ks * 32)
                         : *(const bf16x8*)&smean[wave * 16 + m][(ks - 4) * 32 + kg * 8];
    const ushort* bb = Bp + (size_t)ks * 4096 + lane * 8;
    #pragma unroll
    for (int t = 0; t < 8; ++t)
      acc[t] = __builtin_amdgcn_mfma_f32_16x16x32_bf16(af, *(const bf16x8*)(bb + t * 512), acc[t], 0, 0, 0);
  }
  #pragma unroll
  for (int t = 0; t < 8; ++t) {
    int c = t * 16 + m;
    float bv = bias[c];
    #pragma unroll
    for (int i = 0; i < 4; ++i) {
      int r = row0 + kg * 4 + i;
      float v = acc[t][i] + bv;
      if (do_relu) v = fmaxf(v, 0.f);
      if (r < N) out[(size_t)r * D + c] = f2b(v);
    }
  }
}

// ======================= fused predictor MLP (MFMA, pos+neg merged) ============
__global__ __launch_bounds__(256) void k_predict_mfma(
    const ushort* __restrict__ h,
    const int* __restrict__ ps, const int* __restrict__ pd,
    const int* __restrict__ ns, const int* __restrict__ nd,
    const ushort* __restrict__ Bp0, const float* __restrict__ bp0,
    const ushort* __restrict__ Bp1, const float* __restrict__ bp1,
    const float* __restrict__ Wp2, const float* __restrict__ bp2,
    float* __restrict__ outp, int P, int pb) {
  __shared__ __align__(16) ushort z1p[4][2048];  // per-wave A-frag-packed z1
  int bi = blockIdx.x;
  const int* sidx; const int* didx; float* op;
  if (bi >= pb) { sidx = ns; didx = nd; op = outp + P; bi -= pb; }
  else          { sidx = ps; didx = pd; op = outp; }
  int tid = threadIdx.x;
  int wave = tid >> 6, lane = tid & 63;
  int m = lane & 15, kg = lane >> 4;
  int pair0 = bi * 64 + wave * 16;
  int prow = pair0 + m; int pr = (prow < P) ? prow : P - 1;
  int si = sidx[pr], di = didx[pr];
  const ushort* hs = h + (size_t)si * D + kg * 8;
  const ushort* hd = h + (size_t)di * D + kg * 8;
  f32x4 acc[8];
  #pragma unroll
  for (int t = 0; t < 8; ++t) acc[t] = f32x4{0.f, 0.f, 0.f, 0.f};
  // ---- GEMM1: z = hs*hd ; acc = z @ Wp0 ----
  #pragma unroll
  for (int ks = 0; ks < 4; ++ks) {
    bf16x8 as8 = *(const bf16x8*)(hs + ks * 32);
    bf16x8 ad8 = *(const bf16x8*)(hd + ks * 32);
    bf16x8 af;
    #pragma unroll
    for (int j = 0; j < 8; ++j) {
      float p = b2f((ushort)as8[j]) * b2f((ushort)ad8[j]);
      af[j] = (short)f2b(p);
    }
    const ushort* bb = Bp0 + (size_t)ks * 4096 + lane * 8;
    #pragma unroll
    for (int t = 0; t < 8; ++t)
      acc[t] = __builtin_amdgcn_mfma_f32_16x16x32_bf16(af, *(const bf16x8*)(bb + t * 512), acc[t], 0, 0, 0);
  }
  // ---- epilogue1: relu(acc + bp0) -> LDS in GEMM2 A-fragment packed order ----
  ushort* zp = &z1p[wave][0];
  #pragma unroll
  for (int t = 0; t < 8; ++t) {
    int c = t * 16 + m;
    float bv = bp0[c];
    int ks2 = c >> 5, kg2 = (c >> 3) & 3, j2 = c & 7;
    #pragma unroll
    for (int i = 0; i < 4; ++i) {
      float v = fmaxf(acc[t][i] + bv, 0.f);
      int l2 = kg2 * 16 + kg * 4 + i;     // consumer lane
      zp[(ks2 * 64 + l2) * 8 + j2] = f2b(v);
    }
  }
  __syncthreads();
  // ---- GEMM2: acc = z1 @ Wp1 ----
  #pragma unroll
  for (int t = 0; t < 8; ++t) acc[t] = f32x4{0.f, 0.f, 0.f, 0.f};
  #pragma unroll
  for (int ks = 0; ks < 4; ++ks) {
    bf16x8 af = *(const bf16x8*)(zp + (ks * 64 + lane) * 8);
    const ushort* bb = Bp1 + (size_t)ks * 4096 + lane * 8;
    #pragma unroll
    for (int t = 0; t < 8; ++t)
      acc[t] = __builtin_amdgcn_mfma_f32_16x16x32_bf16(af, *(const bf16x8*)(bb + t * 512), acc[t], 0, 0, 0);
  }
  // ---- final: z2 = relu(acc + bp1); logits = z2 @ Wp2 + bp2; sigmoid ----
  float p0[4] = {0.f, 0.f, 0.f, 0.f}, p1[4] = {0.f, 0.f, 0.f, 0.f};
  #pragma unroll
  for (int t = 0; t < 8; ++t) {
    int c = t * 16 + m;
    float bv = bp1[c];
    float wa = Wp2[(size_t)c * 2], wb = Wp2[(size_t)c * 2 + 1];
    #pragma unroll
    for (int i = 0; i < 4; ++i) {
      float z = fmaxf(acc[t][i] + bv, 0.f);
      p0[i] += z * wa;
      p1[i] += z * wb;
    }
  }
  #pragma unroll
  for (int msk = 1; msk <= 8; msk <<= 1) {
    #pragma unroll
    for (int i = 0; i < 4; ++i) {
      p0[i] += __shfl_xor(p0[i], msk);
      p1[i] += __shfl_xor(p1[i], msk);
    }
  }
  if (m == 0) {
    float c0 = bp2[0], c1 = bp2[1];
    #pragma unroll
    for (int i = 0; i < 4; ++i) {
      int r = pair0 + kg * 4 + i;
      if (r < P) {
        float l0 = p0[i] + c0, l1 = p1[i] + c1;
        op[r] = 1.0f / (1.0f + expf(l0 - l1));
      }
    }
  }
}

// ======================= launch =======================
extern "C" void kernel_launch(void* const* d_in, const int* in_sizes, int n_in,
                              void* d_out, int out_size, void* d_ws, size_t ws_size,
                              hipStream_t stream) {
  const float* x       = (const float*)d_in[0];
  const int*   src     = (const int*)d_in[1];
  const int*   dst     = (const int*)d_in[2];
  const int*   pos_src = (const int*)d_in[3];
  const int*   pos_dst = (const int*)d_in[4];
  const int*   neg_src = (const int*)d_in[5];
  const int*   neg_dst = (const int*)d_in[6];
  const float* Ws0 = (const float*)d_in[7],  *Wn0 = (const float*)d_in[8],  *b0 = (const float*)d_in[9];
  const float* Ws1 = (const float*)d_in[10], *Wn1 = (const float*)d_in[11], *b1 = (const float*)d_in[12];
  const float* Ws2 = (const float*)d_in[13], *Wn2 = (const float*)d_in[14], *b2 = (const float*)d_in[15];
  const float* Wp0 = (const float*)d_in[16], *bp0 = (const float*)d_in[17];
  const float* Wp1 = (const float*)d_in[18], *bp1 = (const float*)d_in[19];
  const float* Wp2 = (const float*)d_in[20], *bp2 = (const float*)d_in[21];
  const int N = in_sizes[0] / D;
  const int E = in_sizes[1];
  const int P = in_sizes[3];
  float* outp = (float*)d_out;

  char* ws = (char*)d_ws;
  size_t off = 0;
  auto alloc = [&](size_t bytes) -> void* {
    void* p = ws + off;
    off += (bytes + 255) & ~(size_t)255;
    return p;
  };
  ushort* xb    = (ushort*)alloc((size_t)N * D * 2);
  ushort* h1    = (ushort*)alloc((size_t)N * D * 2);
  ushort* h2    = (ushort*)alloc((size_t)N * D * 2);
  ushort* BpL0  = (ushort*)alloc(256 * D * 2);
  ushort* BpL1  = (ushort*)alloc(256 * D * 2);
  ushort* BpL2  = (ushort*)alloc(256 * D * 2);
  ushort* BpP0  = (ushort*)alloc(128 * D * 2);
  ushort* BpP1  = (ushort*)alloc(128 * D * 2);
  int*    deg    = (int*)alloc((size_t)N * 4);
  int*    rowptr = (int*)alloc((size_t)(N + 1) * 4);
  int*    cursor = (int*)alloc((size_t)N * 4);
  int*    part   = (int*)alloc(4096);
  int*    csrc   = (int*)alloc((size_t)E * 4);
  (void)ws_size; (void)n_in; (void)out_size;

  const float pscale = 8.0f / (float)N;
  const int CB = 96;                           // blocks per part
  const int CE = (E + CB - 1) / CB;            // edges per chunk

  // --- CSR build (XCD-partitioned) ---
  hipMemsetAsync(deg, 0, (size_t)N * 4, stream);
  k_degree_p<<<8 * CB, 256, 0, stream>>>(dst, E, deg, pscale, CE);
  int nb = (N + SCAN_CHUNK - 1) / SCAN_CHUNK;
  k_scan_partial<<<nb, SCAN_T, 0, stream>>>(deg, N, part);
  k_scan_part_ex<<<1, 1024, 0, stream>>>(part, nb);
  k_scan_final<<<nb, SCAN_T, 0, stream>>>(deg, N, part, rowptr, cursor, E);
  k_fill_p<<<8 * CB, 256, 0, stream>>>(src, dst, E, cursor, csrc, pscale, CE);

  // --- conversions / weight packing ---
  int n8 = N * D / 8;
  k_conv_bf16<<<(n8 + 255) / 256, 256, 0, stream>>>(x, xb, n8);
  k_pack_all<<<512, 256, 0, stream>>>(Ws0, Wn0, Ws1, Wn1, Ws2, Wn2, Wp0, Wp1,
                                      BpL0, BpL1, BpL2, BpP0, BpP1);

  int gemb = (N + 63) / 64;
  k_sage_fused<<<gemb, 256, 0, stream>>>(xb, rowptr, csrc, BpL0, b0, h1, N, 1);
  k_sage_fused<<<gemb, 256, 0, stream>>>(h1, rowptr, csrc, BpL1, b1, h2, N, 1);
  k_sage_fused<<<gemb, 256, 0, stream>>>(h2, rowptr, csrc, BpL2, b2, xb, N, 0);

  int pb = (P + 63) / 64;
  k_predict_mfma<<<2 * pb, 256, 0, stream>>>(xb, pos_src, pos_dst, neg_src, neg_dst,
                                             BpP0, bp0, BpP1, bp1, Wp2, bp2, outp, P, pb);
}

// Round 6
// 466.133 us; speedup vs baseline: 2.0832x; 1.0043x over previous
//
#include <hip/hip_runtime.h>
#include <cstdint>
#include <cstddef>
#include <cmath>

#define D 128

typedef short bf16x8 __attribute__((ext_vector_type(8)));
typedef float f32x4 __attribute__((ext_vector_type(4)));

__device__ __forceinline__ ushort f2b(float f) {
  uint x = __float_as_uint(f);
  uint r = ((x >> 16) & 1u) + 0x7fffu;   // round-to-nearest-even
  return (ushort)((x + r) >> 16);
}
__device__ __forceinline__ float b2f(ushort u) {
  return __uint_as_float(((uint)u) << 16);
}

// ======================= CSR build (XCD-partitioned) =======================
__global__ __launch_bounds__(256) void k_degree_p(const int* __restrict__ dst, int E,
    int* __restrict__ deg, float scale, int CE) {
  int part = blockIdx.x & 7, chunk = blockIdx.x >> 3;
  long base = (long)chunk * CE;
  for (int i = threadIdx.x; i < CE; i += 256) {
    long e = base + i;
    if (e < E) {
      int d = dst[e];
      int p = (int)((float)d * scale); if (p > 7) p = 7;
      if (p == part) atomicAdd(&deg[d], 1);
    }
  }
}

__global__ __launch_bounds__(256) void k_fill_p(const int* __restrict__ src,
    const int* __restrict__ dst, int E, int* __restrict__ cursor,
    int* __restrict__ csrc, float scale, int CE) {
  int part = blockIdx.x & 7, chunk = blockIdx.x >> 3;
  long base = (long)chunk * CE;
  for (int i = threadIdx.x; i < CE; i += 256) {
    long e = base + i;
    if (e < E) {
      int d = dst[e];
      int p = (int)((float)d * scale); if (p > 7) p = 7;
      if (p == part) {
        int s = src[e];
        int pos = atomicAdd(&cursor[d], 1);
        csrc[pos] = s;
      }
    }
  }
}

#define SCAN_T 256
#define SCAN_E 4
#define SCAN_CHUNK (SCAN_T * SCAN_E)

__global__ void k_scan_partial(const int* __restrict__ deg, int n, int* __restrict__ part) {
  __shared__ int s[SCAN_T];
  int base = blockIdx.x * SCAN_CHUNK;
  int sum = 0;
  for (int i = 0; i < SCAN_E; ++i) {
    int idx = base + (int)threadIdx.x * SCAN_E + i;
    if (idx < n) sum += deg[idx];
  }
  s[threadIdx.x] = sum; __syncthreads();
  for (int ofs = SCAN_T / 2; ofs > 0; ofs >>= 1) {
    if ((int)threadIdx.x < ofs) s[threadIdx.x] += s[threadIdx.x + ofs];
    __syncthreads();
  }
  if (threadIdx.x == 0) part[blockIdx.x] = s[0];
}

__global__ void k_scan_part_ex(int* __restrict__ part, int nb) {
  __shared__ int s[1024];
  int v = ((int)threadIdx.x < nb) ? part[threadIdx.x] : 0;
  s[threadIdx.x] = v; __syncthreads();
  for (int ofs = 1; ofs < 1024; ofs <<= 1) {
    int t = ((int)threadIdx.x >= ofs) ? s[threadIdx.x - ofs] : 0;
    __syncthreads();
    s[threadIdx.x] += t;
    __syncthreads();
  }
  if ((int)threadIdx.x < nb) part[threadIdx.x] = s[threadIdx.x] - v;  // exclusive
}

__global__ void k_scan_final(const int* __restrict__ deg, int n, const int* __restrict__ part,
                             int* __restrict__ rowptr, int* __restrict__ cursor, int E) {
  __shared__ int s[SCAN_T];
  int base = blockIdx.x * SCAN_CHUNK;
  int v[SCAN_E]; int local = 0;
  for (int i = 0; i < SCAN_E; ++i) {
    int idx = base + (int)threadIdx.x * SCAN_E + i;
    v[i] = (idx < n) ? deg[idx] : 0;
    local += v[i];
  }
  s[threadIdx.x] = local; __syncthreads();
  for (int ofs = 1; ofs < SCAN_T; ofs <<= 1) {
    int t = ((int)threadIdx.x >= ofs) ? s[threadIdx.x - ofs] : 0;
    __syncthreads();
    s[threadIdx.x] += t;
    __syncthreads();
  }
  int run = part[blockIdx.x] + s[threadIdx.x] - local;  // exclusive prefix
  for (int i = 0; i < SCAN_E; ++i) {
    int idx = base + (int)threadIdx.x * SCAN_E + i;
    if (idx < n) { rowptr[idx] = run; cursor[idx] = run; }
    run += v[i];
  }
  if (blockIdx.x == 0 && threadIdx.x == 0) rowptr[n] = E;
}

// ======================= fp32 -> bf16 convert =======================
__global__ void k_conv_bf16(const float* __restrict__ in, ushort* __restrict__ out, int n8) {
  int i = blockIdx.x * 256 + threadIdx.x;
  if (i >= n8) return;
  float4 a = ((const float4*)in)[i * 2];
  float4 b = ((const float4*)in)[i * 2 + 1];
  ushort4 o0 = {f2b(a.x), f2b(a.y), f2b(a.z), f2b(a.w)};
  ushort4 o1 = {f2b(b.x), f2b(b.y), f2b(b.z), f2b(b.w)};
  ((ushort4*)out)[i * 2] = o0;
  ((ushort4*)out)[i * 2 + 1] = o1;
}

// ======================= pack ALL weights to B-fragment order ==================
// packed[((ks*8 + t)*64 + lane)*8 + j] = W[ks*32 + (lane>>4)*8 + j][t*16 + (lane&15)]
// virtual W: k<128 -> W0[k][n], k>=128 -> W1[k-128][n]
__global__ void k_pack_all(
    const float* __restrict__ Ws0, const float* __restrict__ Wn0,
    const float* __restrict__ Ws1, const float* __restrict__ Wn1,
    const float* __restrict__ Ws2, const float* __restrict__ Wn2,
    const float* __restrict__ Wp0, const float* __restrict__ Wp1,
    ushort* __restrict__ BpL0, ushort* __restrict__ BpL1, ushort* __restrict__ BpL2,
    ushort* __restrict__ BpP0, ushort* __restrict__ BpP1) {
  int o = blockIdx.x * 256 + threadIdx.x;   // total 131072
  const float *W0, *W1; ushort* out; int rel;
  if (o < 32768)       { W0 = Ws0; W1 = Wn0; out = BpL0; rel = o; }
  else if (o < 65536)  { W0 = Ws1; W1 = Wn1; out = BpL1; rel = o - 32768; }
  else if (o < 98304)  { W0 = Ws2; W1 = Wn2; out = BpL2; rel = o - 65536; }
  else if (o < 114688) { W0 = Wp0; W1 = Wp0; out = BpP0; rel = o - 98304; }
  else                 { W0 = Wp1; W1 = Wp1; out = BpP1; rel = o - 114688; }
  int j = rel & 7, lane = (rel >> 3) & 63, t = (rel >> 9) & 7, ks = rel >> 12;
  int k = ks * 32 + ((lane >> 4) * 8) + j;
  int n = t * 16 + (lane & 15);
  const float* W = (k < 128) ? W0 : W1;
  int kk = (k < 128) ? k : k - 128;
  out[rel] = f2b(W[(size_t)kk * D + n]);
}

// ======================= fused aggregate + SAGE GEMM =======================
// Block = 64 rows (4 waves x 16 for MFMA). Gather: 16 independent 16-lane
// groups, each owning 4 whole nodes. Two-phase gather breaks the
// csrc->row dependency chain: (A) lane sub prefetches csrc[beg[j]+sub]
// (first 16 edge indices of each node, ONE round trip), (B) row loop gets
// addresses via __shfl of the prefetched regs (VALU only) -> row loads
// issue back-to-back, 4 nodes interleaved x2 unroll = 8 rows in flight,
// zero index round trips inside the loop. deg>16 tail: serial fallback.
#define SMS 136
__global__ __launch_bounds__(256) void k_sage_fused(
    const ushort* __restrict__ A, const int* __restrict__ rowptr,
    const int* __restrict__ csrc, const ushort* __restrict__ Bp,
    const float* __restrict__ bias, ushort* __restrict__ out, int N, int do_relu) {
  __shared__ __align__(16) ushort smean[64][SMS];
  int tid = threadIdx.x, wave = tid >> 6, lane = tid & 63;
  int m = lane & 15, kg = lane >> 4;        // MFMA roles
  int g = tid >> 4, sub = tid & 15;         // gather roles: 16 groups of 16
  int gb = (lane >> 4) << 4;                // group base lane within wave
  const ushort* hb = A + sub * 8;

  // ---- phase A: rowptr + edge-index prefetch ----
  int node0 = blockIdx.x * 64 + g * 4;
  int rpv = 0;
  if (sub < 5) { int ix = node0 + sub; if (ix > N) ix = N; rpv = rowptr[ix]; }
  int beg[4], end[4], dd[4];
  #pragma unroll
  for (int j = 0; j < 4; ++j) {
    beg[j] = __shfl(rpv, gb + j);
    end[j] = __shfl(rpv, gb + j + 1);
    int dg = end[j] - beg[j];
    dd[j] = dg < 16 ? dg : 16;
  }
  int idxv[4];
  #pragma unroll
  for (int j = 0; j < 4; ++j) {
    int i = beg[j] + sub;
    idxv[j] = (i < end[j]) ? csrc[i] : 0;
  }

  // ---- phase B: pipelined row gather ----
  float f[4][8];
  #pragma unroll
  for (int j = 0; j < 4; ++j)
    #pragma unroll
    for (int q = 0; q < 8; ++q) f[j][q] = 0.f;

  int maxdd = dd[0];
  if (dd[1] > maxdd) maxdd = dd[1];
  if (dd[2] > maxdd) maxdd = dd[2];
  if (dd[3] > maxdd) maxdd = dd[3];

  for (int e = 0; e < maxdd; e += 2) {
    #pragma unroll
    for (int j = 0; j < 4; ++j) {
      int s0 = __shfl(idxv[j], gb + e);
      int s1 = __shfl(idxv[j], gb + e + 1);
      if (e < dd[j]) {
        bf16x8 r0 = *(const bf16x8*)(hb + (size_t)s0 * D);
        #pragma unroll
        for (int q = 0; q < 8; ++q) f[j][q] += b2f((ushort)r0[q]);
      }
      if (e + 1 < dd[j]) {
        bf16x8 r1 = *(const bf16x8*)(hb + (size_t)s1 * D);
        #pragma unroll
        for (int q = 0; q < 8; ++q) f[j][q] += b2f((ushort)r1[q]);
      }
    }
  }
  // rare deg>16 tail
  #pragma unroll
  for (int j = 0; j < 4; ++j) {
    for (int i = beg[j] + 16; i < end[j]; ++i) {
      int s = csrc[i];
      bf16x8 v = *(const bf16x8*)(hb + (size_t)s * D);
      #pragma unroll
      for (int q = 0; q < 8; ++q) f[j][q] += b2f((ushort)v[q]);
    }
  }
  // write means to LDS
  #pragma unroll
  for (int j = 0; j < 4; ++j) {
    int dg = end[j] - beg[j];
    float inv = (dg > 0) ? (1.0f / (float)dg) : 0.0f;
    bf16x8 o;
    #pragma unroll
    for (int q = 0; q < 8; ++q) o[q] = (short)f2b(f[j][q] * inv);
    *(bf16x8*)&smean[g * 4 + j][sub * 8] = o;
  }
  __syncthreads();

  // ---- MFMA phase ----
  int row0 = blockIdx.x * 64 + wave * 16;
  int ar = row0 + m; if (ar >= N) ar = N - 1;   // clamp reads; stores guarded
  const ushort* a_self = A + (size_t)ar * D + kg * 8;
  f32x4 acc[8];
  #pragma unroll
  for (int t = 0; t < 8; ++t) acc[t] = f32x4{0.f, 0.f, 0.f, 0.f};
  #pragma unroll
  for (int ks = 0; ks < 8; ++ks) {
    bf16x8 af = (ks < 4) ? *(const bf16x8*)(a_self + ks * 32)
                         : *(const bf16x8*)&smean[wave * 16 + m][(ks - 4) * 32 + kg * 8];
    const ushort* bb = Bp + (size_t)ks * 4096 + lane * 8;
    #pragma unroll
    for (int t = 0; t < 8; ++t)
      acc[t] = __builtin_amdgcn_mfma_f32_16x16x32_bf16(af, *(const bf16x8*)(bb + t * 512), acc[t], 0, 0, 0);
  }
  #pragma unroll
  for (int t = 0; t < 8; ++t) {
    int c = t * 16 + m;
    float bv = bias[c];
    #pragma unroll
    for (int i = 0; i < 4; ++i) {
      int r = row0 + kg * 4 + i;
      float v = acc[t][i] + bv;
      if (do_relu) v = fmaxf(v, 0.f);
      if (r < N) out[(size_t)r * D + c] = f2b(v);
    }
  }
}

// ======================= fused predictor MLP (MFMA, pos+neg merged) ============
__global__ __launch_bounds__(256) void k_predict_mfma(
    const ushort* __restrict__ h,
    const int* __restrict__ ps, const int* __restrict__ pd,
    const int* __restrict__ ns, const int* __restrict__ nd,
    const ushort* __restrict__ Bp0, const float* __restrict__ bp0,
    const ushort* __restrict__ Bp1, const float* __restrict__ bp1,
    const float* __restrict__ Wp2, const float* __restrict__ bp2,
    float* __restrict__ outp, int P, int pb) {
  __shared__ __align__(16) ushort z1p[4][2048];  // per-wave A-frag-packed z1
  int bi = blockIdx.x;
  const int* sidx; const int* didx; float* op;
  if (bi >= pb) { sidx = ns; didx = nd; op = outp + P; bi -= pb; }
  else          { sidx = ps; didx = pd; op = outp; }
  int tid = threadIdx.x;
  int wave = tid >> 6, lane = tid & 63;
  int m = lane & 15, kg = lane >> 4;
  int pair0 = bi * 64 + wave * 16;
  int prow = pair0 + m; int pr = (prow < P) ? prow : P - 1;
  int si = sidx[pr], di = didx[pr];
  const ushort* hs = h + (size_t)si * D + kg * 8;
  const ushort* hd = h + (size_t)di * D + kg * 8;
  f32x4 acc[8];
  #pragma unroll
  for (int t = 0; t < 8; ++t) acc[t] = f32x4{0.f, 0.f, 0.f, 0.f};
  // ---- GEMM1: z = hs*hd ; acc = z @ Wp0 ----
  #pragma unroll
  for (int ks = 0; ks < 4; ++ks) {
    bf16x8 as8 = *(const bf16x8*)(hs + ks * 32);
    bf16x8 ad8 = *(const bf16x8*)(hd + ks * 32);
    bf16x8 af;
    #pragma unroll
    for (int j = 0; j < 8; ++j) {
      float p = b2f((ushort)as8[j]) * b2f((ushort)ad8[j]);
      af[j] = (short)f2b(p);
    }
    const ushort* bb = Bp0 + (size_t)ks * 4096 + lane * 8;
    #pragma unroll
    for (int t = 0; t < 8; ++t)
      acc[t] = __builtin_amdgcn_mfma_f32_16x16x32_bf16(af, *(const bf16x8*)(bb + t * 512), acc[t], 0, 0, 0);
  }
  // ---- epilogue1: relu(acc + bp0) -> LDS in GEMM2 A-fragment packed order ----
  ushort* zp = &z1p[wave][0];
  #pragma unroll
  for (int t = 0; t < 8; ++t) {
    int c = t * 16 + m;
    float bv = bp0[c];
    int ks2 = c >> 5, kg2 = (c >> 3) & 3, j2 = c & 7;
    #pragma unroll
    for (int i = 0; i < 4; ++i) {
      float v = fmaxf(acc[t][i] + bv, 0.f);
      int l2 = kg2 * 16 + kg * 4 + i;     // consumer lane
      zp[(ks2 * 64 + l2) * 8 + j2] = f2b(v);
    }
  }
  __syncthreads();
  // ---- GEMM2: acc = z1 @ Wp1 ----
  #pragma unroll
  for (int t = 0; t < 8; ++t) acc[t] = f32x4{0.f, 0.f, 0.f, 0.f};
  #pragma unroll
  for (int ks = 0; ks < 4; ++ks) {
    bf16x8 af = *(const bf16x8*)(zp + (ks * 64 + lane) * 8);
    const ushort* bb = Bp1 + (size_t)ks * 4096 + lane * 8;
    #pragma unroll
    for (int t = 0; t < 8; ++t)
      acc[t] = __builtin_amdgcn_mfma_f32_16x16x32_bf16(af, *(const bf16x8*)(bb + t * 512), acc[t], 0, 0, 0);
  }
  // ---- final: z2 = relu(acc + bp1); logits = z2 @ Wp2 + bp2; sigmoid ----
  float p0[4] = {0.f, 0.f, 0.f, 0.f}, p1[4] = {0.f, 0.f, 0.f, 0.f};
  #pragma unroll
  for (int t = 0; t < 8; ++t) {
    int c = t * 16 + m;
    float bv = bp1[c];
    float wa = Wp2[(size_t)c * 2], wb = Wp2[(size_t)c * 2 + 1];
    #pragma unroll
    for (int i = 0; i < 4; ++i) {
      float z = fmaxf(acc[t][i] + bv, 0.f);
      p0[i] += z * wa;
      p1[i] += z * wb;
    }
  }
  #pragma unroll
  for (int msk = 1; msk <= 8; msk <<= 1) {
    #pragma unroll
    for (int i = 0; i < 4; ++i) {
      p0[i] += __shfl_xor(p0[i], msk);
      p1[i] += __shfl_xor(p1[i], msk);
    }
  }
  if (m == 0) {
    float c0 = bp2[0], c1 = bp2[1];
    #pragma unroll
    for (int i = 0; i < 4; ++i) {
      int r = pair0 + kg * 4 + i;
      if (r < P) {
        float l0 = p0[i] + c0, l1 = p1[i] + c1;
        op[r] = 1.0f / (1.0f + expf(l0 - l1));
      }
    }
  }
}

// ======================= launch =======================
extern "C" void kernel_launch(void* const* d_in, const int* in_sizes, int n_in,
                              void* d_out, int out_size, void* d_ws, size_t ws_size,
                              hipStream_t stream) {
  const float* x       = (const float*)d_in[0];
  const int*   src     = (const int*)d_in[1];
  const int*   dst     = (const int*)d_in[2];
  const int*   pos_src = (const int*)d_in[3];
  const int*   pos_dst = (const int*)d_in[4];
  const int*   neg_src = (const int*)d_in[5];
  const int*   neg_dst = (const int*)d_in[6];
  const float* Ws0 = (const float*)d_in[7],  *Wn0 = (const float*)d_in[8],  *b0 = (const float*)d_in[9];
  const float* Ws1 = (const float*)d_in[10], *Wn1 = (const float*)d_in[11], *b1 = (const float*)d_in[12];
  const float* Ws2 = (const float*)d_in[13], *Wn2 = (const float*)d_in[14], *b2 = (const float*)d_in[15];
  const float* Wp0 = (const float*)d_in[16], *bp0 = (const float*)d_in[17];
  const float* Wp1 = (const float*)d_in[18], *bp1 = (const float*)d_in[19];
  const float* Wp2 = (const float*)d_in[20], *bp2 = (const float*)d_in[21];
  const int N = in_sizes[0] / D;
  const int E = in_sizes[1];
  const int P = in_sizes[3];
  float* outp = (float*)d_out;

  char* ws = (char*)d_ws;
  size_t off = 0;
  auto alloc = [&](size_t bytes) -> void* {
    void* p = ws + off;
    off += (bytes + 255) & ~(size_t)255;
    return p;
  };
  ushort* xb    = (ushort*)alloc((size_t)N * D * 2);
  ushort* h1    = (ushort*)alloc((size_t)N * D * 2);
  ushort* h2    = (ushort*)alloc((size_t)N * D * 2);
  ushort* BpL0  = (ushort*)alloc(256 * D * 2);
  ushort* BpL1  = (ushort*)alloc(256 * D * 2);
  ushort* BpL2  = (ushort*)alloc(256 * D * 2);
  ushort* BpP0  = (ushort*)alloc(128 * D * 2);
  ushort* BpP1  = (ushort*)alloc(128 * D * 2);
  int*    deg    = (int*)alloc((size_t)N * 4);
  int*    rowptr = (int*)alloc((size_t)(N + 1) * 4);
  int*    cursor = (int*)alloc((size_t)N * 4);
  int*    part   = (int*)alloc(4096);
  int*    csrc   = (int*)alloc((size_t)E * 4);
  (void)ws_size; (void)n_in; (void)out_size;

  const float pscale = 8.0f / (float)N;
  const int CB = 96;                           // blocks per part
  const int CE = (E + CB - 1) / CB;            // edges per chunk

  // --- CSR build (XCD-partitioned) ---
  hipMemsetAsync(deg, 0, (size_t)N * 4, stream);
  k_degree_p<<<8 * CB, 256, 0, stream>>>(dst, E, deg, pscale, CE);
  int nb = (N + SCAN_CHUNK - 1) / SCAN_CHUNK;
  k_scan_partial<<<nb, SCAN_T, 0, stream>>>(deg, N, part);
  k_scan_part_ex<<<1, 1024, 0, stream>>>(part, nb);
  k_scan_final<<<nb, SCAN_T, 0, stream>>>(deg, N, part, rowptr, cursor, E);
  k_fill_p<<<8 * CB, 256, 0, stream>>>(src, dst, E, cursor, csrc, pscale, CE);

  // --- conversions / weight packing ---
  int n8 = N * D / 8;
  k_conv_bf16<<<(n8 + 255) / 256, 256, 0, stream>>>(x, xb, n8);
  k_pack_all<<<512, 256, 0, stream>>>(Ws0, Wn0, Ws1, Wn1, Ws2, Wn2, Wp0, Wp1,
                                      BpL0, BpL1, BpL2, BpP0, BpP1);

  int gemb = (N + 63) / 64;
  k_sage_fused<<<gemb, 256, 0, stream>>>(xb, rowptr, csrc, BpL0, b0, h1, N, 1);
  k_sage_fused<<<gemb, 256, 0, stream>>>(h1, rowptr, csrc, BpL1, b1, h2, N, 1);
  k_sage_fused<<<gemb, 256, 0, stream>>>(h2, rowptr, csrc, BpL2, b2, xb, N, 0);

  int pb = (P + 63) / 64;
  k_predict_mfma<<<2 * pb, 256, 0, stream>>>(xb, pos_src, pos_dst, neg_src, neg_dst,
                                             BpP0, bp0, BpP1, bp1, Wp2, bp2, outp, P, pb);
}

// Round 7
// 463.606 us; speedup vs baseline: 2.0946x; 1.0055x over previous
//
#include <hip/hip_runtime.h>
#include <cstdint>
#include <cstddef>
#include <cmath>

#define D 128

typedef short bf16x8 __attribute__((ext_vector_type(8)));
typedef float f32x4 __attribute__((ext_vector_type(4)));

__device__ __forceinline__ ushort f2b(float f) {
  uint x = __float_as_uint(f);
  uint r = ((x >> 16) & 1u) + 0x7fffu;   // round-to-nearest-even
  return (ushort)((x + r) >> 16);
}
__device__ __forceinline__ float b2f(ushort u) {
  return __uint_as_float(((uint)u) << 16);
}

// ======================= CSR build (XCD-partitioned) =======================
__global__ __launch_bounds__(256) void k_degree_p(const int* __restrict__ dst, int E,
    int* __restrict__ deg, float scale, int CE) {
  int part = blockIdx.x & 7, chunk = blockIdx.x >> 3;
  long base = (long)chunk * CE;
  for (int i = threadIdx.x; i < CE; i += 256) {
    long e = base + i;
    if (e < E) {
      int d = dst[e];
      int p = (int)((float)d * scale); if (p > 7) p = 7;
      if (p == part) atomicAdd(&deg[d], 1);
    }
  }
}

__global__ __launch_bounds__(256) void k_fill_p(const int* __restrict__ src,
    const int* __restrict__ dst, int E, int* __restrict__ cursor,
    int* __restrict__ csrc, float scale, int CE) {
  int part = blockIdx.x & 7, chunk = blockIdx.x >> 3;
  long base = (long)chunk * CE;
  for (int i = threadIdx.x; i < CE; i += 256) {
    long e = base + i;
    if (e < E) {
      int d = dst[e];
      int p = (int)((float)d * scale); if (p > 7) p = 7;
      if (p == part) {
        int s = src[e];
        int pos = atomicAdd(&cursor[d], 1);
        csrc[pos] = s;
      }
    }
  }
}

#define SCAN_T 256
#define SCAN_E 4
#define SCAN_CHUNK (SCAN_T * SCAN_E)

__global__ void k_scan_partial(const int* __restrict__ deg, int n, int* __restrict__ part) {
  __shared__ int s[SCAN_T];
  int base = blockIdx.x * SCAN_CHUNK;
  int sum = 0;
  for (int i = 0; i < SCAN_E; ++i) {
    int idx = base + (int)threadIdx.x * SCAN_E + i;
    if (idx < n) sum += deg[idx];
  }
  s[threadIdx.x] = sum; __syncthreads();
  for (int ofs = SCAN_T / 2; ofs > 0; ofs >>= 1) {
    if ((int)threadIdx.x < ofs) s[threadIdx.x] += s[threadIdx.x + ofs];
    __syncthreads();
  }
  if (threadIdx.x == 0) part[blockIdx.x] = s[0];
}

__global__ void k_scan_part_ex(int* __restrict__ part, int nb) {
  __shared__ int s[1024];
  int v = ((int)threadIdx.x < nb) ? part[threadIdx.x] : 0;
  s[threadIdx.x] = v; __syncthreads();
  for (int ofs = 1; ofs < 1024; ofs <<= 1) {
    int t = ((int)threadIdx.x >= ofs) ? s[threadIdx.x - ofs] : 0;
    __syncthreads();
    s[threadIdx.x] += t;
    __syncthreads();
  }
  if ((int)threadIdx.x < nb) part[threadIdx.x] = s[threadIdx.x] - v;  // exclusive
}

__global__ void k_scan_final(const int* __restrict__ deg, int n, const int* __restrict__ part,
                             int* __restrict__ rowptr, int* __restrict__ cursor, int E) {
  __shared__ int s[SCAN_T];
  int base = blockIdx.x * SCAN_CHUNK;
  int v[SCAN_E]; int local = 0;
  for (int i = 0; i < SCAN_E; ++i) {
    int idx = base + (int)threadIdx.x * SCAN_E + i;
    v[i] = (idx < n) ? deg[idx] : 0;
    local += v[i];
  }
  s[threadIdx.x] = local; __syncthreads();
  for (int ofs = 1; ofs < SCAN_T; ofs <<= 1) {
    int t = ((int)threadIdx.x >= ofs) ? s[threadIdx.x - ofs] : 0;
    __syncthreads();
    s[threadIdx.x] += t;
    __syncthreads();
  }
  int run = part[blockIdx.x] + s[threadIdx.x] - local;  // exclusive prefix
  for (int i = 0; i < SCAN_E; ++i) {
    int idx = base + (int)threadIdx.x * SCAN_E + i;
    if (idx < n) { rowptr[idx] = run; cursor[idx] = run; }
    run += v[i];
  }
  if (blockIdx.x == 0 && threadIdx.x == 0) rowptr[n] = E;
}

// ======================= fp32 -> bf16 convert =======================
__global__ void k_conv_bf16(const float* __restrict__ in, ushort* __restrict__ out, int n8) {
  int i = blockIdx.x * 256 + threadIdx.x;
  if (i >= n8) return;
  float4 a = ((const float4*)in)[i * 2];
  float4 b = ((const float4*)in)[i * 2 + 1];
  ushort4 o0 = {f2b(a.x), f2b(a.y), f2b(a.z), f2b(a.w)};
  ushort4 o1 = {f2b(b.x), f2b(b.y), f2b(b.z), f2b(b.w)};
  ((ushort4*)out)[i * 2] = o0;
  ((ushort4*)out)[i * 2 + 1] = o1;
}

// ======================= pack ALL weights to B-fragment order ==================
__global__ void k_pack_all(
    const float* __restrict__ Ws0, const float* __restrict__ Wn0,
    const float* __restrict__ Ws1, const float* __restrict__ Wn1,
    const float* __restrict__ Ws2, const float* __restrict__ Wn2,
    const float* __restrict__ Wp0, const float* __restrict__ Wp1,
    ushort* __restrict__ BpL0, ushort* __restrict__ BpL1, ushort* __restrict__ BpL2,
    ushort* __restrict__ BpP0, ushort* __restrict__ BpP1) {
  int o = blockIdx.x * 256 + threadIdx.x;   // total 131072
  const float *W0, *W1; ushort* out; int rel;
  if (o < 32768)       { W0 = Ws0; W1 = Wn0; out = BpL0; rel = o; }
  else if (o < 65536)  { W0 = Ws1; W1 = Wn1; out = BpL1; rel = o - 32768; }
  else if (o < 98304)  { W0 = Ws2; W1 = Wn2; out = BpL2; rel = o - 65536; }
  else if (o < 114688) { W0 = Wp0; W1 = Wp0; out = BpP0; rel = o - 98304; }
  else                 { W0 = Wp1; W1 = Wp1; out = BpP1; rel = o - 114688; }
  int j = rel & 7, lane = (rel >> 3) & 63, t = (rel >> 9) & 7, ks = rel >> 12;
  int k = ks * 32 + ((lane >> 4) * 8) + j;
  int n = t * 16 + (lane & 15);
  const float* W = (k < 128) ? W0 : W1;
  int kk = (k < 128) ? k : k - 128;
  out[rel] = f2b(W[(size_t)kk * D + n]);
}

// ======================= fused aggregate + SAGE GEMM =======================
// Block = 128 threads = 2 INDEPENDENT wave-tiles of 16 rows each. Per wave:
// 4 gather groups x 16 lanes, each group owns 4 nodes (two-phase: index
// prefetch then shfl-addressed pipelined row loads). Mean rows go to the
// wave's private LDS slab; MFMA phase reads them back as A-frags. Small
// blocks -> ~2x resident waves/CU and per-wave (not per-4-wave) degree
// load balance.
#define SMS 136
__global__ __launch_bounds__(128) void k_sage_fused(
    const ushort* __restrict__ A, const int* __restrict__ rowptr,
    const int* __restrict__ csrc, const ushort* __restrict__ Bp,
    const float* __restrict__ bias, ushort* __restrict__ out, int N, int do_relu) {
  __shared__ __align__(16) ushort smean[2][16][SMS];   // 8704 B
  int tid = threadIdx.x, wave = tid >> 6, lane = tid & 63;
  int m = lane & 15, kg = lane >> 4;        // MFMA roles
  int g = kg, sub = m;                      // gather roles: 4 groups of 16
  int gb = g << 4;                          // group base lane
  int row0 = (blockIdx.x * 2 + wave) * 16;  // this wave's 16-row tile
  const ushort* hb = A + sub * 8;

  // ---- phase A: rowptr + edge-index prefetch ----
  int node0 = row0 + g * 4;
  int rpv = 0;
  if (sub < 5) { int ix = node0 + sub; if (ix > N) ix = N; rpv = rowptr[ix]; }
  int beg[4], end[4], dd[4];
  #pragma unroll
  for (int j = 0; j < 4; ++j) {
    beg[j] = __shfl(rpv, gb + j);
    end[j] = __shfl(rpv, gb + j + 1);
    int dg = end[j] - beg[j];
    dd[j] = dg < 16 ? dg : 16;
  }
  int idxv[4];
  #pragma unroll
  for (int j = 0; j < 4; ++j) {
    int i = beg[j] + sub;
    idxv[j] = (i < end[j]) ? csrc[i] : 0;
  }

  // ---- phase B: pipelined row gather ----
  float f[4][8];
  #pragma unroll
  for (int j = 0; j < 4; ++j)
    #pragma unroll
    for (int q = 0; q < 8; ++q) f[j][q] = 0.f;

  int maxdd = dd[0];
  if (dd[1] > maxdd) maxdd = dd[1];
  if (dd[2] > maxdd) maxdd = dd[2];
  if (dd[3] > maxdd) maxdd = dd[3];

  for (int e = 0; e < maxdd; e += 2) {
    #pragma unroll
    for (int j = 0; j < 4; ++j) {
      int s0 = __shfl(idxv[j], gb + e);
      int s1 = __shfl(idxv[j], gb + e + 1);
      if (e < dd[j]) {
        bf16x8 r0 = *(const bf16x8*)(hb + (size_t)s0 * D);
        #pragma unroll
        for (int q = 0; q < 8; ++q) f[j][q] += b2f((ushort)r0[q]);
      }
      if (e + 1 < dd[j]) {
        bf16x8 r1 = *(const bf16x8*)(hb + (size_t)s1 * D);
        #pragma unroll
        for (int q = 0; q < 8; ++q) f[j][q] += b2f((ushort)r1[q]);
      }
    }
  }
  // rare deg>16 tail
  #pragma unroll
  for (int j = 0; j < 4; ++j) {
    for (int i = beg[j] + 16; i < end[j]; ++i) {
      int s = csrc[i];
      bf16x8 v = *(const bf16x8*)(hb + (size_t)s * D);
      #pragma unroll
      for (int q = 0; q < 8; ++q) f[j][q] += b2f((ushort)v[q]);
    }
  }
  // write means to this wave's LDS slab
  #pragma unroll
  for (int j = 0; j < 4; ++j) {
    int dg = end[j] - beg[j];
    float inv = (dg > 0) ? (1.0f / (float)dg) : 0.0f;
    bf16x8 o;
    #pragma unroll
    for (int q = 0; q < 8; ++q) o[q] = (short)f2b(f[j][q] * inv);
    *(bf16x8*)&smean[wave][g * 4 + j][sub * 8] = o;
  }
  __syncthreads();

  // ---- MFMA phase ----
  int ar = row0 + m; if (ar >= N) ar = N - 1;   // clamp reads; stores guarded
  const ushort* a_self = A + (size_t)ar * D + kg * 8;
  f32x4 acc[8];
  #pragma unroll
  for (int t = 0; t < 8; ++t) acc[t] = f32x4{0.f, 0.f, 0.f, 0.f};
  #pragma unroll
  for (int ks = 0; ks < 8; ++ks) {
    bf16x8 af = (ks < 4) ? *(const bf16x8*)(a_self + ks * 32)
                         : *(const bf16x8*)&smean[wave][m][(ks - 4) * 32 + kg * 8];
    const ushort* bb = Bp + (size_t)ks * 4096 + lane * 8;
    #pragma unroll
    for (int t = 0; t < 8; ++t)
      acc[t] = __builtin_amdgcn_mfma_f32_16x16x32_bf16(af, *(const bf16x8*)(bb + t * 512), acc[t], 0, 0, 0);
  }
  #pragma unroll
  for (int t = 0; t < 8; ++t) {
    int c = t * 16 + m;
    float bv = bias[c];
    #pragma unroll
    for (int i = 0; i < 4; ++i) {
      int r = row0 + kg * 4 + i;
      float v = acc[t][i] + bv;
      if (do_relu) v = fmaxf(v, 0.f);
      if (r < N) out[(size_t)r * D + c] = f2b(v);
    }
  }
}

// ======================= fused predictor MLP (MFMA, pos+neg merged) ============
__global__ __launch_bounds__(256) void k_predict_mfma(
    const ushort* __restrict__ h,
    const int* __restrict__ ps, const int* __restrict__ pd,
    const int* __restrict__ ns, const int* __restrict__ nd,
    const ushort* __restrict__ Bp0, const float* __restrict__ bp0,
    const ushort* __restrict__ Bp1, const float* __restrict__ bp1,
    const float* __restrict__ Wp2, const float* __restrict__ bp2,
    float* __restrict__ outp, int P, int pb) {
  __shared__ __align__(16) ushort z1p[4][2048];  // per-wave A-frag-packed z1
  int bi = blockIdx.x;
  const int* sidx; const int* didx; float* op;
  if (bi >= pb) { sidx = ns; didx = nd; op = outp + P; bi -= pb; }
  else          { sidx = ps; didx = pd; op = outp; }
  int tid = threadIdx.x;
  int wave = tid >> 6, lane = tid & 63;
  int m = lane & 15, kg = lane >> 4;
  int pair0 = bi * 64 + wave * 16;
  int prow = pair0 + m; int pr = (prow < P) ? prow : P - 1;
  int si = sidx[pr], di = didx[pr];
  const ushort* hs = h + (size_t)si * D + kg * 8;
  const ushort* hd = h + (size_t)di * D + kg * 8;
  f32x4 acc[8];
  #pragma unroll
  for (int t = 0; t < 8; ++t) acc[t] = f32x4{0.f, 0.f, 0.f, 0.f};
  // ---- GEMM1: z = hs*hd ; acc = z @ Wp0 ----
  #pragma unroll
  for (int ks = 0; ks < 4; ++ks) {
    bf16x8 as8 = *(const bf16x8*)(hs + ks * 32);
    bf16x8 ad8 = *(const bf16x8*)(hd + ks * 32);
    bf16x8 af;
    #pragma unroll
    for (int j = 0; j < 8; ++j) {
      float p = b2f((ushort)as8[j]) * b2f((ushort)ad8[j]);
      af[j] = (short)f2b(p);
    }
    const ushort* bb = Bp0 + (size_t)ks * 4096 + lane * 8;
    #pragma unroll
    for (int t = 0; t < 8; ++t)
      acc[t] = __builtin_amdgcn_mfma_f32_16x16x32_bf16(af, *(const bf16x8*)(bb + t * 512), acc[t], 0, 0, 0);
  }
  // ---- epilogue1: relu(acc + bp0) -> LDS in GEMM2 A-fragment packed order ----
  ushort* zp = &z1p[wave][0];
  #pragma unroll
  for (int t = 0; t < 8; ++t) {
    int c = t * 16 + m;
    float bv = bp0[c];
    int ks2 = c >> 5, kg2 = (c >> 3) & 3, j2 = c & 7;
    #pragma unroll
    for (int i = 0; i < 4; ++i) {
      float v = fmaxf(acc[t][i] + bv, 0.f);
      int l2 = kg2 * 16 + kg * 4 + i;     // consumer lane
      zp[(ks2 * 64 + l2) * 8 + j2] = f2b(v);
    }
  }
  __syncthreads();
  // ---- GEMM2: acc = z1 @ Wp1 ----
  #pragma unroll
  for (int t = 0; t < 8; ++t) acc[t] = f32x4{0.f, 0.f, 0.f, 0.f};
  #pragma unroll
  for (int ks = 0; ks < 4; ++ks) {
    bf16x8 af = *(const bf16x8*)(zp + (ks * 64 + lane) * 8);
    const ushort* bb = Bp1 + (size_t)ks * 4096 + lane * 8;
    #pragma unroll
    for (int t = 0; t < 8; ++t)
      acc[t] = __builtin_amdgcn_mfma_f32_16x16x32_bf16(af, *(const bf16x8*)(bb + t * 512), acc[t], 0, 0, 0);
  }
  // ---- final: z2 = relu(acc + bp1); logits = z2 @ Wp2 + bp2; sigmoid ----
  float p0[4] = {0.f, 0.f, 0.f, 0.f}, p1[4] = {0.f, 0.f, 0.f, 0.f};
  #pragma unroll
  for (int t = 0; t < 8; ++t) {
    int c = t * 16 + m;
    float bv = bp1[c];
    float wa = Wp2[(size_t)c * 2], wb = Wp2[(size_t)c * 2 + 1];
    #pragma unroll
    for (int i = 0; i < 4; ++i) {
      float z = fmaxf(acc[t][i] + bv, 0.f);
      p0[i] += z * wa;
      p1[i] += z * wb;
    }
  }
  #pragma unroll
  for (int msk = 1; msk <= 8; msk <<= 1) {
    #pragma unroll
    for (int i = 0; i < 4; ++i) {
      p0[i] += __shfl_xor(p0[i], msk);
      p1[i] += __shfl_xor(p1[i], msk);
    }
  }
  if (m == 0) {
    float c0 = bp2[0], c1 = bp2[1];
    #pragma unroll
    for (int i = 0; i < 4; ++i) {
      int r = pair0 + kg * 4 + i;
      if (r < P) {
        float l0 = p0[i] + c0, l1 = p1[i] + c1;
        op[r] = 1.0f / (1.0f + expf(l0 - l1));
      }
    }
  }
}

// ======================= launch =======================
extern "C" void kernel_launch(void* const* d_in, const int* in_sizes, int n_in,
                              void* d_out, int out_size, void* d_ws, size_t ws_size,
                              hipStream_t stream) {
  const float* x       = (const float*)d_in[0];
  const int*   src     = (const int*)d_in[1];
  const int*   dst     = (const int*)d_in[2];
  const int*   pos_src = (const int*)d_in[3];
  const int*   pos_dst = (const int*)d_in[4];
  const int*   neg_src = (const int*)d_in[5];
  const int*   neg_dst = (const int*)d_in[6];
  const float* Ws0 = (const float*)d_in[7],  *Wn0 = (const float*)d_in[8],  *b0 = (const float*)d_in[9];
  const float* Ws1 = (const float*)d_in[10], *Wn1 = (const float*)d_in[11], *b1 = (const float*)d_in[12];
  const float* Ws2 = (const float*)d_in[13], *Wn2 = (const float*)d_in[14], *b2 = (const float*)d_in[15];
  const float* Wp0 = (const float*)d_in[16], *bp0 = (const float*)d_in[17];
  const float* Wp1 = (const float*)d_in[18], *bp1 = (const float*)d_in[19];
  const float* Wp2 = (const float*)d_in[20], *bp2 = (const float*)d_in[21];
  const int N = in_sizes[0] / D;
  const int E = in_sizes[1];
  const int P = in_sizes[3];
  float* outp = (float*)d_out;

  char* ws = (char*)d_ws;
  size_t off = 0;
  auto alloc = [&](size_t bytes) -> void* {
    void* p = ws + off;
    off += (bytes + 255) & ~(size_t)255;
    return p;
  };
  ushort* xb    = (ushort*)alloc((size_t)N * D * 2);
  ushort* h1    = (ushort*)alloc((size_t)N * D * 2);
  ushort* h2    = (ushort*)alloc((size_t)N * D * 2);
  ushort* BpL0  = (ushort*)alloc(256 * D * 2);
  ushort* BpL1  = (ushort*)alloc(256 * D * 2);
  ushort* BpL2  = (ushort*)alloc(256 * D * 2);
  ushort* BpP0  = (ushort*)alloc(128 * D * 2);
  ushort* BpP1  = (ushort*)alloc(128 * D * 2);
  int*    deg    = (int*)alloc((size_t)N * 4);
  int*    rowptr = (int*)alloc((size_t)(N + 1) * 4);
  int*    cursor = (int*)alloc((size_t)N * 4);
  int*    part   = (int*)alloc(4096);
  int*    csrc   = (int*)alloc((size_t)E * 4);
  (void)ws_size; (void)n_in; (void)out_size;

  const float pscale = 8.0f / (float)N;
  const int CB = 96;                           // blocks per part
  const int CE = (E + CB - 1) / CB;            // edges per chunk

  // --- CSR build (XCD-partitioned) ---
  hipMemsetAsync(deg, 0, (size_t)N * 4, stream);
  k_degree_p<<<8 * CB, 256, 0, stream>>>(dst, E, deg, pscale, CE);
  int nb = (N + SCAN_CHUNK - 1) / SCAN_CHUNK;
  k_scan_partial<<<nb, SCAN_T, 0, stream>>>(deg, N, part);
  k_scan_part_ex<<<1, 1024, 0, stream>>>(part, nb);
  k_scan_final<<<nb, SCAN_T, 0, stream>>>(deg, N, part, rowptr, cursor, E);
  k_fill_p<<<8 * CB, 256, 0, stream>>>(src, dst, E, cursor, csrc, pscale, CE);

  // --- conversions / weight packing ---
  int n8 = N * D / 8;
  k_conv_bf16<<<(n8 + 255) / 256, 256, 0, stream>>>(x, xb, n8);
  k_pack_all<<<512, 256, 0, stream>>>(Ws0, Wn0, Ws1, Wn1, Ws2, Wn2, Wp0, Wp1,
                                      BpL0, BpL1, BpL2, BpP0, BpP1);

  int gemb = (N + 31) / 32;
  k_sage_fused<<<gemb, 128, 0, stream>>>(xb, rowptr, csrc, BpL0, b0, h1, N, 1);
  k_sage_fused<<<gemb, 128, 0, stream>>>(h1, rowptr, csrc, BpL1, b1, h2, N, 1);
  k_sage_fused<<<gemb, 128, 0, stream>>>(h2, rowptr, csrc, BpL2, b2, xb, N, 0);

  int pb = (P + 63) / 64;
  k_predict_mfma<<<2 * pb, 256, 0, stream>>>(xb, pos_src, pos_dst, neg_src, neg_dst,
                                             BpP0, bp0, BpP1, bp1, Wp2, bp2, outp, P, pb);
}